// Round 12
// baseline (735.834 us; speedup 1.0000x reference)
//
#include <hip/hip_runtime.h>
#include <stdint.h>
#include <math.h>

// ---------------------------------------------------------------------------
// PAAE layer, MI355X (gfx950). Round 12: 256x256 MX-fp8 GEMM.
// R11 audit: 128^2/4-wave geometry gives 44 FLOP per LDS byte < the 59
// needed to feed the MX pipe (7585 FLOP/cyc vs 128 B/cyc LDS) -> LDS-bound
// by construction. 256^2/8-wave gives 87 FLOP/B -> MFMA-bound. Double-buffered
// 128KB LDS (1 block/CU), 2-phase stage-ahead + one vmcnt(0)+barrier per
// K-tile (R11 protocol), loop unrolled 2x with literal buffer indices
// (removes dynamic-buf VALU addressing; VALUBusy was 60%), A-frags in two
// batches of 4 to cap VGPR. Epilogue/wave mapping = verified R6 256^2 code.
// ---------------------------------------------------------------------------

typedef short short8 __attribute__((ext_vector_type(8)));
typedef unsigned short ushort8 __attribute__((ext_vector_type(8)));
typedef unsigned char uchar8 __attribute__((ext_vector_type(8)));
typedef float f32x4 __attribute__((ext_vector_type(4)));
typedef int int4v __attribute__((ext_vector_type(4)));
typedef int int8v __attribute__((ext_vector_type(8)));

#define DEVI static __device__ __forceinline__

DEVI unsigned short f2bf(float f) {  // RNE float -> bf16 bits
  uint32_t u = __builtin_bit_cast(uint32_t, f);
  return (unsigned short)((u + 0x7fffu + ((u >> 16) & 1u)) >> 16);
}
DEVI unsigned char f2fp8(float f) {  // RNE float -> OCP e4m3fn
  uint32_t u = __builtin_bit_cast(uint32_t, f);
  uint32_t s = (u >> 24) & 0x80u;
  uint32_t a = u & 0x7fffffffu;
  if (a >= 0x43e00000u) return (unsigned char)(s | 0x7eu);  // sat to 448
  if (a < 0x3c800000u) {  // |f| < 2^-6 -> subnormal, step 2^-9
    float af = __builtin_bit_cast(float, a);
    uint32_t n = (uint32_t)__builtin_rintf(af * 512.0f);
    return (unsigned char)(s | n);
  }
  uint32_t r = a + 0xfffffu + ((a >> 20) & 1u);
  return (unsigned char)(s | ((r >> 20) - 960u));
}
DEVI float sigmoidf_(float x) { return 1.0f / (1.0f + expf(-x)); }

DEVI void gld16(const void* g, void* l) {
  __builtin_amdgcn_global_load_lds(
      (const __attribute__((address_space(1))) unsigned int*)g,
      (__attribute__((address_space(3))) unsigned int*)l, 16, 0, 0);
}

#define MFMA16B(a, b, c) __builtin_amdgcn_mfma_f32_16x16x32_bf16(a, b, c, 0, 0, 0)
#define MFMAMX(a, b, c)                                              \
  __builtin_amdgcn_mfma_scale_f32_16x16x128_f8f6f4(                  \
      a, b, c, 0, 0, 0, 0x7f7f7f7fu, 0, 0x7f7f7f7fu)

// ---------------------------------------------------------------------------
__global__ __launch_bounds__(256) void k_f32_to_bf16(
    const float* __restrict__ s, unsigned short* __restrict__ d, long n) {
  long i0 = ((long)blockIdx.x * 256 + threadIdx.x) * 8;
  long stride = (long)gridDim.x * 256 * 8;
  for (long i = i0; i < n; i += stride) {
    f32x4 a = *(const f32x4*)(s + i);
    f32x4 b = *(const f32x4*)(s + i + 4);
    ushort8 o;
    o[0] = f2bf(a[0]); o[1] = f2bf(a[1]); o[2] = f2bf(a[2]); o[3] = f2bf(a[3]);
    o[4] = f2bf(b[0]); o[5] = f2bf(b[1]); o[6] = f2bf(b[2]); o[7] = f2bf(b[3]);
    *(ushort8*)(d + i) = o;
  }
}

__global__ __launch_bounds__(256) void k_f32_to_fp8(
    const float* __restrict__ s, unsigned char* __restrict__ d, long n,
    float scale) {
  long i0 = ((long)blockIdx.x * 256 + threadIdx.x) * 8;
  long stride = (long)gridDim.x * 256 * 8;
  for (long i = i0; i < n; i += stride) {
    f32x4 a = *(const f32x4*)(s + i);
    f32x4 b = *(const f32x4*)(s + i + 4);
    uchar8 o;
    o[0] = f2fp8(a[0] * scale); o[1] = f2fp8(a[1] * scale);
    o[2] = f2fp8(a[2] * scale); o[3] = f2fp8(a[3] * scale);
    o[4] = f2fp8(b[0] * scale); o[5] = f2fp8(b[1] * scale);
    o[6] = f2fp8(b[2] * scale); o[7] = f2fp8(b[3] * scale);
    *(uchar8*)(d + i) = o;
  }
}

// ---------------------------------------------------------------------------
// MX-fp8 GEMM, 256x256 tile, BK=128, 8 waves, double-buffered 128KB LDS.
// C[M,N] = A[M,K]*B[N,K]^T, A/B e4m3 row-major, K%256==0.
// LDS row = 128 B (8 chunks); chunk c stored at c^(row&7) (inverse-swizzled
// global source, linear gld16 dest); frag reads XOR the same.
// Frag (16x16x128): lane l: row=l&15, k=(l>>4)*32+0..31 (2 b128 chunks).
// Waves: wr=wid>>2 (128 rows), wc=wid&3 (64 cols). Per wave: a-frags 8
// (read in 2 batches of 4), b-frags 4.
// EPI 0: outF[z*zsf + row*N + col] = acc*dsc   (z = branch)
// EPI 1: outB[z] = e4m3(tanh(acc*dsc + bias[row]))
// ---------------------------------------------------------------------------
template <int EPI>
__global__ __launch_bounds__(512, 1) void k_gemmMX(
    const unsigned char* __restrict__ A0, const unsigned char* __restrict__ A1,
    const unsigned char* __restrict__ B0, const unsigned char* __restrict__ B1,
    float* __restrict__ outF, unsigned char* __restrict__ oB0,
    unsigned char* __restrict__ oB1, const float* __restrict__ bias0,
    const float* __restrict__ bias1, int M, int N, int K, long zsf,
    float dsc) {
  // XCD-aware bijective swizzle of the xy-plane (plane size % 8 == 0)
  const int gx = gridDim.x;
  const int nwg = gx * gridDim.y;
  const int flat = blockIdx.y * gx + blockIdx.x;
  const int swz = (flat & 7) * (nwg >> 3) + (flat >> 3);
  const int bxi = swz % gx, byi = swz / gx;

  const int bz = blockIdx.z;
  const unsigned char* A = bz ? A1 : A0;
  const unsigned char* B = bz ? B1 : B0;
  unsigned char* outB = bz ? oB1 : oB0;
  const float* bias = bz ? bias1 : bias0;

  __shared__ unsigned char lds[2][2][32768];  // [buf][op] 256 rows x 128 B
  const int tid = threadIdx.x, lane = tid & 63;
  const int wid = tid >> 6, wr = wid >> 2, wc = wid & 3;
  const int bm = bxi * 256, bn = byi * 256;
  const int rl = lane & 15, q = lane >> 4;

  // fragment read offsets: two b128 chunks per 32B fragment
  const int x7 = rl & 7;
  const int c0 = ((2 * q) ^ x7) << 4;
  const int c1 = ((2 * q + 1) ^ x7) << 4;

  // staging: 4 x 16B chunks per thread per operand (512 thr x 4 x 16B = 32KB)
  size_t soff[4];
  int dsto[4];
#pragma unroll
  for (int i = 0; i < 4; i++) {
    const int cid = tid + 512 * i;
    const int r = cid >> 3, c = cid & 7;
    soff[i] = (size_t)r * K + ((c ^ (r & 7)) << 4);
    dsto[i] = cid << 4;
  }

  const unsigned char* gA = A + (size_t)bm * K;
  const unsigned char* gB = B + (size_t)bn * K;

  auto stage = [&](int kc, int buf) {
#pragma unroll
    for (int i = 0; i < 4; i++) {
      gld16(gA + kc + soff[i], &lds[buf][0][dsto[i]]);
      gld16(gB + kc + soff[i], &lds[buf][1][dsto[i]]);
    }
  };

  f32x4 acc[8][4] = {};

  // one K-tile: compute from buf bc, prefetch tile kc+128 into bn_
  auto body = [&](int kc, int bc, int bn_) {
    if (kc + 128 < K) stage(kc + 128, bn_);

    const unsigned char* As = &lds[bc][0][0];
    const unsigned char* Bs = &lds[bc][1][0];

    int8v bf[4];
#pragma unroll
    for (int nf = 0; nf < 4; nf++) {
      const unsigned char* p = Bs + (wc * 64 + nf * 16 + rl) * 128;
      int4v lo = *(const int4v*)(p + c0);
      int4v hi = *(const int4v*)(p + c1);
      bf[nf] = __builtin_shufflevector(lo, hi, 0, 1, 2, 3, 4, 5, 6, 7);
    }
    int8v af[4];
#pragma unroll
    for (int mi = 0; mi < 4; mi++) {
      const unsigned char* p = As + (wr * 128 + mi * 16 + rl) * 128;
      int4v lo = *(const int4v*)(p + c0);
      int4v hi = *(const int4v*)(p + c1);
      af[mi] = __builtin_shufflevector(lo, hi, 0, 1, 2, 3, 4, 5, 6, 7);
    }
    __builtin_amdgcn_s_setprio(1);
#pragma unroll
    for (int mi = 0; mi < 4; mi++)
#pragma unroll
      for (int nf = 0; nf < 4; nf++)
        acc[mi][nf] = MFMAMX(af[mi], bf[nf], acc[mi][nf]);
    __builtin_amdgcn_s_setprio(0);
#pragma unroll
    for (int mi = 0; mi < 4; mi++) {
      const unsigned char* p = As + (wr * 128 + (4 + mi) * 16 + rl) * 128;
      int4v lo = *(const int4v*)(p + c0);
      int4v hi = *(const int4v*)(p + c1);
      af[mi] = __builtin_shufflevector(lo, hi, 0, 1, 2, 3, 4, 5, 6, 7);
    }
    __builtin_amdgcn_s_setprio(1);
#pragma unroll
    for (int mi = 0; mi < 4; mi++)
#pragma unroll
      for (int nf = 0; nf < 4; nf++)
        acc[4 + mi][nf] = MFMAMX(af[mi], bf[nf], acc[4 + mi][nf]);
    __builtin_amdgcn_s_setprio(0);

    if (kc + 128 < K) {
      // next tile staged + all waves done reading buf bc
      asm volatile("s_waitcnt vmcnt(0)\ns_barrier" ::: "memory");
    }
  };

  stage(0, 0);
  asm volatile("s_waitcnt vmcnt(0)\ns_barrier" ::: "memory");

  for (int k0 = 0; k0 < K; k0 += 256) {
    body(k0, 0, 1);
    body(k0 + 128, 1, 0);
  }

#pragma unroll
  for (int m = 0; m < 8; m++) {
#pragma unroll
    for (int nf = 0; nf < 4; nf++) {
      const int col = bn + wc * 64 + nf * 16 + rl;
#pragma unroll
      for (int r = 0; r < 4; r++) {
        const int row = bm + wr * 128 + m * 16 + q * 4 + r;
        const float v = acc[m][nf][r] * dsc;
        if (EPI == 0)
          outF[(long)bz * zsf + (size_t)row * N + col] = v;
        else
          outB[(size_t)row * N + col] = f2fp8(tanhf(v + bias[row]));
      }
    }
  }
}

// ---------------------------------------------------------------------------
// h = e4m3(tanh(relu(x @ mw^T + mb))), fused over branches (z = branch).
// ---------------------------------------------------------------------------
__global__ __launch_bounds__(256) void k_gemmH(
    const unsigned short* __restrict__ A0, const unsigned short* __restrict__ A1,
    const unsigned short* __restrict__ B0, const unsigned short* __restrict__ B1,
    unsigned char* __restrict__ o0, unsigned char* __restrict__ o1,
    const float* __restrict__ bias0, const float* __restrict__ bias1, int M,
    int N, int K) {
  const int bz = blockIdx.z;
  const unsigned short* A = bz ? A1 : A0;
  const unsigned short* B = bz ? B1 : B0;
  unsigned char* out8 = bz ? o1 : o0;
  const float* bias = bz ? bias1 : bias0;

  __shared__ unsigned short As[128 * 32];
  __shared__ unsigned short Bs[128 * 32];
  const int tid = threadIdx.x, lane = tid & 63, wid = tid >> 6;
  const int wr = wid >> 1, wc = wid & 1;
  const int bm = blockIdx.x * 128, bn = blockIdx.y * 128;
  const int c0 = tid, c1 = tid + 256;
  const int s0 = ((c0 & 3) ^ ((c0 >> 3) & 3)) << 3;
  const int s1 = ((c1 & 3) ^ ((c1 >> 3) & 3)) << 3;
  const int rl = lane & 15, q = lane >> 4;
  const int qe = (q ^ ((rl >> 1) & 3)) << 3;

  f32x4 acc[4][4] = {};

  for (int k0 = 0; k0 < K; k0 += 32) {
    gld16(A + (size_t)(bm + (c0 >> 2)) * K + k0 + s0, As + c0 * 8);
    gld16(A + (size_t)(bm + (c1 >> 2)) * K + k0 + s1, As + c1 * 8);
    gld16(B + (size_t)(bn + (c0 >> 2)) * K + k0 + s0, Bs + c0 * 8);
    gld16(B + (size_t)(bn + (c1 >> 2)) * K + k0 + s1, Bs + c1 * 8);
    __syncthreads();

    short8 af[4], bfr[4];
#pragma unroll
    for (int mi = 0; mi < 4; mi++)
      af[mi] = *(const short8*)(As + (wr * 64 + mi * 16 + rl) * 32 + qe);
#pragma unroll
    for (int ni = 0; ni < 4; ni++)
      bfr[ni] = *(const short8*)(Bs + (wc * 64 + ni * 16 + rl) * 32 + qe);
#pragma unroll
    for (int mi = 0; mi < 4; mi++)
#pragma unroll
      for (int ni = 0; ni < 4; ni++)
        acc[mi][ni] = MFMA16B(af[mi], bfr[ni], acc[mi][ni]);
    __syncthreads();
  }

#pragma unroll
  for (int mi = 0; mi < 4; mi++) {
#pragma unroll
    for (int ni = 0; ni < 4; ni++) {
      const int col = bn + wc * 64 + ni * 16 + rl;
#pragma unroll
      for (int r = 0; r < 4; r++) {
        const int row = bm + wr * 64 + mi * 16 + q * 4 + r;
        out8[(size_t)row * N + col] =
            f2fp8(tanhf(fmaxf(acc[mi][ni][r] + bias[col], 0.0f)));
      }
    }
  }
}

// ---------------------------------------------------------------------------
// Skinny GEMM, N=64, split-K. grid: (M/64, KS, nbr)
// ---------------------------------------------------------------------------
template <int AMODE, int BMODE>
__global__ __launch_bounds__(256) void k_sgemm64s(
    const void* __restrict__ A0, const void* __restrict__ A1,
    const void* __restrict__ B0, const void* __restrict__ B1,
    float* __restrict__ P, int kchunk, int lda, int ldb, int M) {
  const int br = blockIdx.z, kz = blockIdx.y, KS = gridDim.y;
  const void* Av = br ? A1 : A0;
  const void* Bv = br ? B1 : B0;

  __shared__ unsigned short As[64 * 40];
  __shared__ unsigned short Bs[64 * 40];
  const int tid = threadIdx.x, lane = tid & 63, w = tid >> 6;
  const int tm = blockIdx.x * 64;

  f32x4 acc[4] = {};
  const int kbeg = kz * kchunk, kend = kbeg + kchunk;

  for (int k0 = kbeg; k0 < kend; k0 += 32) {
    if (AMODE == 0) {
      const float* Af = (const float*)Av;
      const int m = tid >> 2, k8 = (tid & 3) << 3;
      f32x4 x0 = *(const f32x4*)(Af + (size_t)(tm + m) * lda + k0 + k8);
      f32x4 x1 = *(const f32x4*)(Af + (size_t)(tm + m) * lda + k0 + k8 + 4);
      ushort8 o;
      o[0] = f2bf(x0[0]); o[1] = f2bf(x0[1]); o[2] = f2bf(x0[2]); o[3] = f2bf(x0[3]);
      o[4] = f2bf(x1[0]); o[5] = f2bf(x1[1]); o[6] = f2bf(x1[2]); o[7] = f2bf(x1[3]);
      *(ushort8*)(As + m * 40 + k8) = o;
    } else if (AMODE == 1) {
      const float* Af = (const float*)Av;
#pragma unroll
      for (int t = 0; t < 2; t++) {
        const int c = tid + t * 256;
        const int u = c >> 4, i4 = (c & 15) << 2;
        f32x4 x = *(const f32x4*)(Af + (size_t)(k0 + u) * lda + tm + i4);
        As[(i4 + 0) * 40 + u] = f2bf(x[0]);
        As[(i4 + 1) * 40 + u] = f2bf(x[1]);
        As[(i4 + 2) * 40 + u] = f2bf(x[2]);
        As[(i4 + 3) * 40 + u] = f2bf(x[3]);
      }
    } else {
      const unsigned short* Ab = (const unsigned short*)Av;
      const int m = tid >> 2, k8 = (tid & 3) << 3;
      *(ushort8*)(As + m * 40 + k8) =
          *(const ushort8*)(Ab + (size_t)(tm + m) * lda + k0 + k8);
    }
    if (BMODE == 0) {
      const float* Bf = (const float*)Bv;
      const int n = tid >> 2, k8 = (tid & 3) << 3;
      f32x4 x0 = *(const f32x4*)(Bf + (size_t)n * ldb + k0 + k8);
      f32x4 x1 = *(const f32x4*)(Bf + (size_t)n * ldb + k0 + k8 + 4);
      ushort8 o;
      o[0] = f2bf(x0[0]); o[1] = f2bf(x0[1]); o[2] = f2bf(x0[2]); o[3] = f2bf(x0[3]);
      o[4] = f2bf(x1[0]); o[5] = f2bf(x1[1]); o[6] = f2bf(x1[2]); o[7] = f2bf(x1[3]);
      *(ushort8*)(Bs + n * 40 + k8) = o;
    } else {
      const unsigned short* Bb = (const unsigned short*)Bv;
      const int n = tid >> 2, k8 = (tid & 3) << 3;
      *(ushort8*)(Bs + n * 40 + k8) =
          *(const ushort8*)(Bb + (size_t)n * ldb + k0 + k8);
    }
    __syncthreads();

    const int kr = (lane >> 4) << 3;
    short8 a = *(const short8*)(As + (w * 16 + (lane & 15)) * 40 + kr);
#pragma unroll
    for (int ni = 0; ni < 4; ni++) {
      short8 bb = *(const short8*)(Bs + (ni * 16 + (lane & 15)) * 40 + kr);
      acc[ni] = MFMA16B(a, bb, acc[ni]);
    }
    __syncthreads();
  }

  float* out = P + ((size_t)(br * KS + kz) * M) * 64;
#pragma unroll
  for (int ni = 0; ni < 4; ni++) {
    const int col = ni * 16 + (lane & 15);
#pragma unroll
    for (int r = 0; r < 4; r++) {
      const int row = tm + w * 16 + ((lane >> 4) << 2) + r;
      out[(size_t)row * 64 + col] = acc[ni][r];
    }
  }
}

// ---------------------------------------------------------------------------
template <int WF, int WB, int WT>
__global__ __launch_bounds__(256) void k_reduce(
    const float* __restrict__ P, size_t pbr_stride, float* F0, float* F1,
    unsigned short* Bo0, unsigned short* Bo1, unsigned short* T0,
    unsigned short* T1, int M, int KS, int ldT) {
  const int br = blockIdx.y;
  const float* Pp = P + (size_t)br * pbr_stride;
  const size_t i = (size_t)blockIdx.x * 256 + threadIdx.x;
  const size_t n = (size_t)M * 64;
  float s = 0.f;
  for (int k = 0; k < KS; k++) s += Pp[(size_t)k * n + i];
  if (WF) (br ? F1 : F0)[i] = s;
  if (WB) (br ? Bo1 : Bo0)[i] = f2bf(s);
  if (WT) {
    const int row = (int)(i >> 6), col = (int)(i & 63);
    (br ? T1 : T0)[(size_t)col * ldT + row] = f2bf(s);
  }
}

// ---------------------------------------------------------------------------
// Row softmax, single f32 slab per branch (z = branch): [2048,4096] -> bf16
// ---------------------------------------------------------------------------
__global__ __launch_bounds__(256) void k_softmax(
    const float* __restrict__ S, unsigned short* __restrict__ P0,
    unsigned short* __restrict__ P1, long slab) {
  const int row = blockIdx.x, br = blockIdx.y, tid = threadIdx.x;
  const float* s = S + (size_t)br * slab + (size_t)row * 4096;
  float v[16];
  float m = -1e30f;
#pragma unroll
  for (int j = 0; j < 16; j++) {
    v[j] = s[tid + j * 256];
    m = fmaxf(m, v[j]);
  }
  __shared__ float red[4], red2[4];
  for (int o = 32; o; o >>= 1) m = fmaxf(m, __shfl_down(m, o));
  if ((tid & 63) == 0) red[tid >> 6] = m;
  __syncthreads();
  m = fmaxf(fmaxf(red[0], red[1]), fmaxf(red[2], red[3]));
  float sum = 0.0f;
#pragma unroll
  for (int j = 0; j < 16; j++) {
    v[j] = expf(v[j] - m);
    sum += v[j];
  }
  for (int o = 32; o; o >>= 1) sum += __shfl_down(sum, o);
  if ((tid & 63) == 0) red2[tid >> 6] = sum;
  __syncthreads();
  const float inv = 1.0f / (red2[0] + red2[1] + red2[2] + red2[3]);
  unsigned short* p = (br ? P1 : P0) + (size_t)row * 4096;
#pragma unroll
  for (int j = 0; j < 16; j++) p[tid + j * 256] = f2bf(v[j] * inv);
}

// ---------------------------------------------------------------------------
__global__ __launch_bounds__(256) void k_user(
    const float* __restrict__ ue_mp, const float* __restrict__ ueat_mp,
    const float* __restrict__ ue_pmp, const float* __restrict__ ueat_pmp,
    const float* __restrict__ mlp_w, const float* __restrict__ mlp_b,
    const float* __restrict__ tr_w, const float* __restrict__ tr_b,
    float* __restrict__ out) {
  const int tid = threadIdx.x, d = tid & 63, w = tid >> 6;
  const int m = blockIdx.x * 4 + w;
  __shared__ float fus[4][64];
  float a1 = mlp_b[d], a2 = a1;
  const float* r1 = ue_mp + (size_t)m * 64;
  const float* r2 = ueat_mp + (size_t)m * 64;
  const float* r3 = ue_pmp + (size_t)m * 64;
  const float* r4 = ueat_pmp + (size_t)m * 64;
  const float* w1 = mlp_w + (size_t)d * 128;
#pragma unroll 8
  for (int k = 0; k < 64; k++) {
    const float wv = w1[k];
    a1 += r1[k] * wv;
    a2 += r3[k] * wv;
  }
#pragma unroll 8
  for (int k = 0; k < 64; k++) {
    const float wv = w1[64 + k];
    a1 += r2[k] * wv;
    a2 += r4[k] * wv;
  }
  const float u1 = sigmoidf_(a1), u2 = sigmoidf_(a2);
  const float rate = sigmoidf_(u1 + u2);
  fus[w][d] = rate * u1 + (1.0f - rate) * u2;
  __syncthreads();
  float o = tr_b[d];
  const float* tw = tr_w + (size_t)d * 64;
#pragma unroll 8
  for (int k = 0; k < 64; k++) o += fus[w][k] * tw[k];
  out[(size_t)m * 64 + d] = tanhf(o);
}

__global__ __launch_bounds__(256) void k_item(
    const float* __restrict__ ie_mp, const float* __restrict__ ie_pmp,
    const float* __restrict__ mlp_w, const float* __restrict__ mlp_b,
    float* __restrict__ out) {
  const int tid = threadIdx.x, d = tid & 63, w = tid >> 6;
  const int i = blockIdx.x * 4 + w;
  float a = mlp_b[d];
  const float* r1 = ie_mp + (size_t)i * 64;
  const float* r2 = ie_pmp + (size_t)i * 64;
  const float* wp = mlp_w + (size_t)d * 128;
#pragma unroll 8
  for (int k = 0; k < 64; k++) {
    a += r1[k] * wp[k];
    a += r2[k] * wp[64 + k];
  }
  out[(size_t)i * 64 + d] = sigmoidf_(a);
}

// ---------------------------------------------------------------------------
extern "C" void kernel_launch(void* const* d_in, const int* in_sizes, int n_in,
                              void* d_out, int out_size, void* d_ws,
                              size_t ws_size, hipStream_t stream) {
  const int U = 2048, I = 4096, D = 64, UI = 6144;
  const float WSC = 16.0f, DSC = 1.0f / 16.0f;

  const float* ui[2] = {(const float*)d_in[0], (const float*)d_in[1]};
  const float* Wu[2] = {(const float*)d_in[2], (const float*)d_in[3]};
  const float* Wi[2] = {(const float*)d_in[4], (const float*)d_in[5]};
  const float* mw[2] = {(const float*)d_in[6], (const float*)d_in[11]};
  const float* mb[2] = {(const float*)d_in[7], (const float*)d_in[12]};
  const float* aw[2] = {(const float*)d_in[8], (const float*)d_in[13]};
  const float* ab[2] = {(const float*)d_in[9], (const float*)d_in[14]};
  const float* Wat[2] = {(const float*)d_in[10], (const float*)d_in[15]};
  const float* mlp_w = (const float*)d_in[16];
  const float* mlp_b = (const float*)d_in[17];
  const float* tr_w = (const float*)d_in[18];
  const float* tr_b = (const float*)d_in[19];

  char* ws = (char*)d_ws;
  size_t off = 0;
  auto alloc = [&](size_t bytes) {
    void* p = ws + off;
    off += (bytes + 255) & ~(size_t)255;
    return p;
  };
  unsigned char* aw_f8[2] = {(unsigned char*)alloc((size_t)I * I),
                             (unsigned char*)alloc((size_t)I * I)};
  unsigned short* mw_bf[2] = {(unsigned short*)alloc((size_t)I * D * 2),
                              (unsigned short*)alloc((size_t)I * D * 2)};
  unsigned char* h_f8[2] = {(unsigned char*)alloc((size_t)UI * I),
                            (unsigned char*)alloc((size_t)UI * I)};
  unsigned char* aT_f8[2] = {(unsigned char*)alloc((size_t)I * UI),
                             (unsigned char*)alloc((size_t)I * UI)};
  float* scores = (float*)alloc((size_t)U * I * 4 * 2);  // 2 branch slabs
  unsigned short* at_bf[2] = {(unsigned short*)alloc((size_t)U * I * 2),
                              (unsigned short*)alloc((size_t)U * I * 2)};
  unsigned short* x_bf[2];
  float* ue_f[2];
  float* ie_f[2];
  unsigned short* ieT[2];
  float* ueat_f[2];
  for (int b = 0; b < 2; b++) {
    x_bf[b] = (unsigned short*)alloc((size_t)UI * D * 2);
    ue_f[b] = (float*)alloc((size_t)U * D * 4);
    ie_f[b] = (float*)alloc((size_t)I * D * 4);
    ieT[b] = (unsigned short*)alloc((size_t)D * I * 2);
    ueat_f[b] = (float*)alloc((size_t)U * D * 4);
  }
  // Lifetime aliases:
  //  pue (8.4MB)  -> h_f8[0] region (dead until h written)
  //  pie (16.8MB) -> aT_f8[0] region (dead until aT written)
  //  pueat (8.4MB)-> scores region (written after softmaxes read it)
  //  Wat_f8[b] (12.6MB) -> at_bf[b] region (written by softmax AFTER scores
  //  consumed Wat_f8 — stream-ordered, safe)
  float* pue = (float*)h_f8[0];
  float* pie = (float*)aT_f8[0];
  float* pueat = scores;
  unsigned char* Wat_f8[2] = {(unsigned char*)at_bf[0],
                              (unsigned char*)at_bf[1]};
  const long zsf = (long)U * I;

  const dim3 blk(256);

  // ue: [U,64] over K=I, both branches, KS=8
  k_sgemm64s<0, 0><<<dim3(U / 64, 8, 2), blk, 0, stream>>>(
      ui[0], ui[1], Wu[0], Wu[1], pue, I / 8, I, I, U);
  k_reduce<1, 1, 0><<<dim3(U * 64 / 256, 2), blk, 0, stream>>>(
      pue, (size_t)8 * U * 64, ue_f[0], ue_f[1], x_bf[0], x_bf[1], nullptr,
      nullptr, U, 8, 0);
  // ie: [I,64] over K=U (A = ui^T), both branches, KS=8
  k_sgemm64s<1, 0><<<dim3(I / 64, 8, 2), blk, 0, stream>>>(
      ui[0], ui[1], Wi[0], Wi[1], pie, U / 8, I, U, I);
  k_reduce<1, 1, 1><<<dim3(I * 64 / 256, 2), blk, 0, stream>>>(
      pie, (size_t)8 * I * 64, ie_f[0], ie_f[1], x_bf[0] + (size_t)U * D,
      x_bf[1] + (size_t)U * D, ieT[0], ieT[1], I, 8, I);

  // converts (all weights, both branches)
  for (int b = 0; b < 2; b++) {
    k_f32_to_fp8<<<2048, blk, 0, stream>>>(aw[b], aw_f8[b], (long)I * I, WSC);
    k_f32_to_fp8<<<2048, blk, 0, stream>>>(Wat[b], Wat_f8[b], (long)U * UI, WSC);
    k_f32_to_bf16<<<128, blk, 0, stream>>>(mw[b], mw_bf[b], (long)I * D);
  }

  // h both branches: [6144,4096], K=64 (z = branch)
  k_gemmH<<<dim3(UI / 128, I / 128, 2), blk, 0, stream>>>(
      x_bf[0], x_bf[1], mw_bf[0], mw_bf[1], h_f8[0], h_f8[1], mb[0], mb[1],
      UI, I, D);

  // aT both branches: [4096,6144], K=4096; 768 blocks = 3 exact rounds
  k_gemmMX<1><<<dim3(I / 256, UI / 256, 2), dim3(512), 0, stream>>>(
      aw_f8[0], aw_f8[1], h_f8[0], h_f8[1], nullptr, aT_f8[0], aT_f8[1],
      ab[0], ab[1], I, UI, I, 0, DSC);

  // scores both branches: [2048,4096], K=6144; 256 blocks = 1 exact round
  k_gemmMX<0><<<dim3(U / 256, I / 256, 2), dim3(512), 0, stream>>>(
      Wat_f8[0], Wat_f8[1], aT_f8[0], aT_f8[1], scores, nullptr, nullptr,
      nullptr, nullptr, U, I, UI, zsf, DSC);

  // softmax both branches (clobbers Wat_f8 alias — Wat dead after scores)
  k_softmax<<<dim3(U, 2), blk, 0, stream>>>(scores, at_bf[0], at_bf[1], zsf);

  // ue_at both branches: [U,64] over K=I, KS=8
  k_sgemm64s<2, 2><<<dim3(U / 64, 8, 2), blk, 0, stream>>>(
      at_bf[0], at_bf[1], ieT[0], ieT[1], pueat, I / 8, I, I, U);
  k_reduce<1, 0, 0><<<dim3(U * 64 / 256, 2), blk, 0, stream>>>(
      pueat, (size_t)8 * U * 64, ueat_f[0], ueat_f[1], nullptr, nullptr,
      nullptr, nullptr, U, 8, 0);

  float* out_user = (float*)d_out;
  float* out_item = (float*)d_out + (size_t)U * D;
  k_user<<<U / 4, blk, 0, stream>>>(ue_f[0], ueat_f[0], ue_f[1], ueat_f[1],
                                    mlp_w, mlp_b, tr_w, tr_b, out_user);
  k_item<<<I / 4, blk, 0, stream>>>(ie_f[0], ie_f[1], mlp_w, mlp_b, out_item);
}

// Round 13
// 714.027 us; speedup vs baseline: 1.0305x; 1.0305x over previous
//
#include <hip/hip_runtime.h>
#include <stdint.h>
#include <math.h>

// ---------------------------------------------------------------------------
// PAAE layer, MI355X (gfx950). Round 13: R12 (256^2 MX-fp8) minus the spill.
// R12 differential: WRITE_SIZE 49->205MB at identical outputs = scratch spill
// in the K-loop (VGPR ran out: acc 128 AGPR + operands 64 + 40 addressing).
// Fix: rematerialize staging offsets from tid inside stage() (int32 offsets),
// flat LDS + literal buffer bases, minimal live scalars. Nothing else moves.
// ---------------------------------------------------------------------------

typedef short short8 __attribute__((ext_vector_type(8)));
typedef unsigned short ushort8 __attribute__((ext_vector_type(8)));
typedef unsigned char uchar8 __attribute__((ext_vector_type(8)));
typedef float f32x4 __attribute__((ext_vector_type(4)));
typedef int int4v __attribute__((ext_vector_type(4)));
typedef int int8v __attribute__((ext_vector_type(8)));

#define DEVI static __device__ __forceinline__

DEVI unsigned short f2bf(float f) {  // RNE float -> bf16 bits
  uint32_t u = __builtin_bit_cast(uint32_t, f);
  return (unsigned short)((u + 0x7fffu + ((u >> 16) & 1u)) >> 16);
}
DEVI unsigned char f2fp8(float f) {  // RNE float -> OCP e4m3fn
  uint32_t u = __builtin_bit_cast(uint32_t, f);
  uint32_t s = (u >> 24) & 0x80u;
  uint32_t a = u & 0x7fffffffu;
  if (a >= 0x43e00000u) return (unsigned char)(s | 0x7eu);  // sat to 448
  if (a < 0x3c800000u) {  // |f| < 2^-6 -> subnormal, step 2^-9
    float af = __builtin_bit_cast(float, a);
    uint32_t n = (uint32_t)__builtin_rintf(af * 512.0f);
    return (unsigned char)(s | n);
  }
  uint32_t r = a + 0xfffffu + ((a >> 20) & 1u);
  return (unsigned char)(s | ((r >> 20) - 960u));
}
DEVI float sigmoidf_(float x) { return 1.0f / (1.0f + expf(-x)); }

DEVI void gld16(const void* g, void* l) {
  __builtin_amdgcn_global_load_lds(
      (const __attribute__((address_space(1))) unsigned int*)g,
      (__attribute__((address_space(3))) unsigned int*)l, 16, 0, 0);
}

#define MFMA16B(a, b, c) __builtin_amdgcn_mfma_f32_16x16x32_bf16(a, b, c, 0, 0, 0)
#define MFMAMX(a, b, c)                                              \
  __builtin_amdgcn_mfma_scale_f32_16x16x128_f8f6f4(                  \
      a, b, c, 0, 0, 0, 0x7f7f7f7fu, 0, 0x7f7f7f7fu)

// ---------------------------------------------------------------------------
__global__ __launch_bounds__(256) void k_f32_to_bf16(
    const float* __restrict__ s, unsigned short* __restrict__ d, long n) {
  long i0 = ((long)blockIdx.x * 256 + threadIdx.x) * 8;
  long stride = (long)gridDim.x * 256 * 8;
  for (long i = i0; i < n; i += stride) {
    f32x4 a = *(const f32x4*)(s + i);
    f32x4 b = *(const f32x4*)(s + i + 4);
    ushort8 o;
    o[0] = f2bf(a[0]); o[1] = f2bf(a[1]); o[2] = f2bf(a[2]); o[3] = f2bf(a[3]);
    o[4] = f2bf(b[0]); o[5] = f2bf(b[1]); o[6] = f2bf(b[2]); o[7] = f2bf(b[3]);
    *(ushort8*)(d + i) = o;
  }
}

__global__ __launch_bounds__(256) void k_f32_to_fp8(
    const float* __restrict__ s, unsigned char* __restrict__ d, long n,
    float scale) {
  long i0 = ((long)blockIdx.x * 256 + threadIdx.x) * 8;
  long stride = (long)gridDim.x * 256 * 8;
  for (long i = i0; i < n; i += stride) {
    f32x4 a = *(const f32x4*)(s + i);
    f32x4 b = *(const f32x4*)(s + i + 4);
    uchar8 o;
    o[0] = f2fp8(a[0] * scale); o[1] = f2fp8(a[1] * scale);
    o[2] = f2fp8(a[2] * scale); o[3] = f2fp8(a[3] * scale);
    o[4] = f2fp8(b[0] * scale); o[5] = f2fp8(b[1] * scale);
    o[6] = f2fp8(b[2] * scale); o[7] = f2fp8(b[3] * scale);
    *(uchar8*)(d + i) = o;
  }
}

// ---------------------------------------------------------------------------
// MX-fp8 GEMM, 256x256 tile, BK=128, 8 waves, double-buffered 128KB LDS.
// C[M,N] = A[M,K]*B[N,K]^T, A/B e4m3 row-major, K%256==0.
// Flat LDS: buf base 0/65536; op base +0 (A) / +32768 (B). Row = 128 B
// (8 chunks of 16B); chunk c stored at c^(row&7) via inverse-swizzled global
// source (linear gld16 dest); frag reads XOR the same.
// Frag (16x16x128): lane l: row=l&15, k=(l>>4)*32+0..31 (2 b128 chunks).
// Waves: wr=wid>>2 (128 rows), wc=wid&3 (64 cols).
// All staging addressing rematerialized from tid inside stage() (anti-spill).
// EPI 0: outF[z*zsf + row*N + col] = acc*dsc   (z = branch)
// EPI 1: outB[z] = e4m3(tanh(acc*dsc + bias[row]))
// ---------------------------------------------------------------------------
template <int EPI>
__global__ __launch_bounds__(512, 1) void k_gemmMX(
    const unsigned char* __restrict__ A0, const unsigned char* __restrict__ A1,
    const unsigned char* __restrict__ B0, const unsigned char* __restrict__ B1,
    float* __restrict__ outF, unsigned char* __restrict__ oB0,
    unsigned char* __restrict__ oB1, const float* __restrict__ bias0,
    const float* __restrict__ bias1, int M, int N, int K, long zsf,
    float dsc) {
  // XCD-aware bijective swizzle of the xy-plane (plane size % 8 == 0)
  const int gx = gridDim.x;
  const int nwg = gx * gridDim.y;
  const int flat = blockIdx.y * gx + blockIdx.x;
  const int swz = (flat & 7) * (nwg >> 3) + (flat >> 3);
  const int bxi = swz % gx, byi = swz / gx;

  const int bz = blockIdx.z;
  const unsigned char* A = bz ? A1 : A0;
  const unsigned char* B = bz ? B1 : B0;
  unsigned char* outB = bz ? oB1 : oB0;
  const float* bias = bz ? bias1 : bias0;

  __shared__ unsigned char lds[131072];
  const int tid = threadIdx.x, lane = tid & 63;
  const int wid = tid >> 6, wr = wid >> 2, wc = wid & 3;
  const int bm = bxi * 256, bn = byi * 256;
  const int rl = lane & 15, q = lane >> 4;

  // fragment read offsets: two b128 chunks per 32B fragment
  const int x7 = rl & 7;
  const int c0 = ((2 * q) ^ x7) << 4;
  const int c1 = ((2 * q + 1) ^ x7) << 4;

  const unsigned char* gA = A + (size_t)bm * K;
  const unsigned char* gB = B + (size_t)bn * K;

  // bufb: literal 0 or 65536. Addressing recomputed from tid each call so the
  // compiler rematerializes instead of keeping 12+ live registers (R12 spill).
  auto stage = [&](int kc, int bufb) {
#pragma unroll
    for (int i = 0; i < 4; i++) {
      const int cid = tid + 512 * i;
      const int r = cid >> 3;
      const int go = r * K + (((cid & 7) ^ (r & 7)) << 4) + kc;  // < 2^31
      const int dst = cid << 4;
      gld16(gA + go, &lds[bufb + dst]);
      gld16(gB + go, &lds[bufb + 32768 + dst]);
    }
  };

  f32x4 acc[8][4] = {};

  // one K-tile: compute from literal buf base cb, prefetch kc+128 into pb
  auto body = [&](int kc, int cb, int pb) {
    if (kc + 128 < K) stage(kc + 128, pb);

    const unsigned char* As = lds + cb;
    const unsigned char* Bs = lds + cb + 32768;

    int8v bf[4];
#pragma unroll
    for (int nf = 0; nf < 4; nf++) {
      const unsigned char* p = Bs + (wc * 64 + nf * 16 + rl) * 128;
      int4v lo = *(const int4v*)(p + c0);
      int4v hi = *(const int4v*)(p + c1);
      bf[nf] = __builtin_shufflevector(lo, hi, 0, 1, 2, 3, 4, 5, 6, 7);
    }
    int8v af[4];
#pragma unroll
    for (int mi = 0; mi < 4; mi++) {
      const unsigned char* p = As + (wr * 128 + mi * 16 + rl) * 128;
      int4v lo = *(const int4v*)(p + c0);
      int4v hi = *(const int4v*)(p + c1);
      af[mi] = __builtin_shufflevector(lo, hi, 0, 1, 2, 3, 4, 5, 6, 7);
    }
    __builtin_amdgcn_s_setprio(1);
#pragma unroll
    for (int mi = 0; mi < 4; mi++)
#pragma unroll
      for (int nf = 0; nf < 4; nf++)
        acc[mi][nf] = MFMAMX(af[mi], bf[nf], acc[mi][nf]);
    __builtin_amdgcn_s_setprio(0);
#pragma unroll
    for (int mi = 0; mi < 4; mi++) {
      const unsigned char* p = As + (wr * 128 + (4 + mi) * 16 + rl) * 128;
      int4v lo = *(const int4v*)(p + c0);
      int4v hi = *(const int4v*)(p + c1);
      af[mi] = __builtin_shufflevector(lo, hi, 0, 1, 2, 3, 4, 5, 6, 7);
    }
    __builtin_amdgcn_s_setprio(1);
#pragma unroll
    for (int mi = 0; mi < 4; mi++)
#pragma unroll
      for (int nf = 0; nf < 4; nf++)
        acc[4 + mi][nf] = MFMAMX(af[mi], bf[nf], acc[4 + mi][nf]);
    __builtin_amdgcn_s_setprio(0);

    if (kc + 128 < K) {
      // next tile staged + all waves done reading buf cb
      asm volatile("s_waitcnt vmcnt(0)\ns_barrier" ::: "memory");
    }
  };

  stage(0, 0);
  asm volatile("s_waitcnt vmcnt(0)\ns_barrier" ::: "memory");

  for (int k0 = 0; k0 < K; k0 += 256) {
    body(k0, 0, 65536);
    body(k0 + 128, 65536, 0);
  }

#pragma unroll
  for (int m = 0; m < 8; m++) {
#pragma unroll
    for (int nf = 0; nf < 4; nf++) {
      const int col = bn + wc * 64 + nf * 16 + rl;
#pragma unroll
      for (int r = 0; r < 4; r++) {
        const int row = bm + wr * 128 + m * 16 + q * 4 + r;
        const float v = acc[m][nf][r] * dsc;
        if (EPI == 0)
          outF[(long)bz * zsf + (size_t)row * N + col] = v;
        else
          outB[(size_t)row * N + col] = f2fp8(tanhf(v + bias[row]));
      }
    }
  }
}

// ---------------------------------------------------------------------------
// h = e4m3(tanh(relu(x @ mw^T + mb))), fused over branches (z = branch).
// ---------------------------------------------------------------------------
__global__ __launch_bounds__(256) void k_gemmH(
    const unsigned short* __restrict__ A0, const unsigned short* __restrict__ A1,
    const unsigned short* __restrict__ B0, const unsigned short* __restrict__ B1,
    unsigned char* __restrict__ o0, unsigned char* __restrict__ o1,
    const float* __restrict__ bias0, const float* __restrict__ bias1, int M,
    int N, int K) {
  const int bz = blockIdx.z;
  const unsigned short* A = bz ? A1 : A0;
  const unsigned short* B = bz ? B1 : B0;
  unsigned char* out8 = bz ? o1 : o0;
  const float* bias = bz ? bias1 : bias0;

  __shared__ unsigned short As[128 * 32];
  __shared__ unsigned short Bs[128 * 32];
  const int tid = threadIdx.x, lane = tid & 63, wid = tid >> 6;
  const int wr = wid >> 1, wc = wid & 1;
  const int bm = blockIdx.x * 128, bn = blockIdx.y * 128;
  const int c0 = tid, c1 = tid + 256;
  const int s0 = ((c0 & 3) ^ ((c0 >> 3) & 3)) << 3;
  const int s1 = ((c1 & 3) ^ ((c1 >> 3) & 3)) << 3;
  const int rl = lane & 15, q = lane >> 4;
  const int qe = (q ^ ((rl >> 1) & 3)) << 3;

  f32x4 acc[4][4] = {};

  for (int k0 = 0; k0 < K; k0 += 32) {
    gld16(A + (size_t)(bm + (c0 >> 2)) * K + k0 + s0, As + c0 * 8);
    gld16(A + (size_t)(bm + (c1 >> 2)) * K + k0 + s1, As + c1 * 8);
    gld16(B + (size_t)(bn + (c0 >> 2)) * K + k0 + s0, Bs + c0 * 8);
    gld16(B + (size_t)(bn + (c1 >> 2)) * K + k0 + s1, Bs + c1 * 8);
    __syncthreads();

    short8 af[4], bfr[4];
#pragma unroll
    for (int mi = 0; mi < 4; mi++)
      af[mi] = *(const short8*)(As + (wr * 64 + mi * 16 + rl) * 32 + qe);
#pragma unroll
    for (int ni = 0; ni < 4; ni++)
      bfr[ni] = *(const short8*)(Bs + (wc * 64 + ni * 16 + rl) * 32 + qe);
#pragma unroll
    for (int mi = 0; mi < 4; mi++)
#pragma unroll
      for (int ni = 0; ni < 4; ni++)
        acc[mi][ni] = MFMA16B(af[mi], bfr[ni], acc[mi][ni]);
    __syncthreads();
  }

#pragma unroll
  for (int mi = 0; mi < 4; mi++) {
#pragma unroll
    for (int ni = 0; ni < 4; ni++) {
      const int col = bn + wc * 64 + ni * 16 + rl;
#pragma unroll
      for (int r = 0; r < 4; r++) {
        const int row = bm + wr * 64 + mi * 16 + q * 4 + r;
        out8[(size_t)row * N + col] =
            f2fp8(tanhf(fmaxf(acc[mi][ni][r] + bias[col], 0.0f)));
      }
    }
  }
}

// ---------------------------------------------------------------------------
// Skinny GEMM, N=64, split-K. grid: (M/64, KS, nbr)
// ---------------------------------------------------------------------------
template <int AMODE, int BMODE>
__global__ __launch_bounds__(256) void k_sgemm64s(
    const void* __restrict__ A0, const void* __restrict__ A1,
    const void* __restrict__ B0, const void* __restrict__ B1,
    float* __restrict__ P, int kchunk, int lda, int ldb, int M) {
  const int br = blockIdx.z, kz = blockIdx.y, KS = gridDim.y;
  const void* Av = br ? A1 : A0;
  const void* Bv = br ? B1 : B0;

  __shared__ unsigned short As[64 * 40];
  __shared__ unsigned short Bs[64 * 40];
  const int tid = threadIdx.x, lane = tid & 63, w = tid >> 6;
  const int tm = blockIdx.x * 64;

  f32x4 acc[4] = {};
  const int kbeg = kz * kchunk, kend = kbeg + kchunk;

  for (int k0 = kbeg; k0 < kend; k0 += 32) {
    if (AMODE == 0) {
      const float* Af = (const float*)Av;
      const int m = tid >> 2, k8 = (tid & 3) << 3;
      f32x4 x0 = *(const f32x4*)(Af + (size_t)(tm + m) * lda + k0 + k8);
      f32x4 x1 = *(const f32x4*)(Af + (size_t)(tm + m) * lda + k0 + k8 + 4);
      ushort8 o;
      o[0] = f2bf(x0[0]); o[1] = f2bf(x0[1]); o[2] = f2bf(x0[2]); o[3] = f2bf(x0[3]);
      o[4] = f2bf(x1[0]); o[5] = f2bf(x1[1]); o[6] = f2bf(x1[2]); o[7] = f2bf(x1[3]);
      *(ushort8*)(As + m * 40 + k8) = o;
    } else if (AMODE == 1) {
      const float* Af = (const float*)Av;
#pragma unroll
      for (int t = 0; t < 2; t++) {
        const int c = tid + t * 256;
        const int u = c >> 4, i4 = (c & 15) << 2;
        f32x4 x = *(const f32x4*)(Af + (size_t)(k0 + u) * lda + tm + i4);
        As[(i4 + 0) * 40 + u] = f2bf(x[0]);
        As[(i4 + 1) * 40 + u] = f2bf(x[1]);
        As[(i4 + 2) * 40 + u] = f2bf(x[2]);
        As[(i4 + 3) * 40 + u] = f2bf(x[3]);
      }
    } else {
      const unsigned short* Ab = (const unsigned short*)Av;
      const int m = tid >> 2, k8 = (tid & 3) << 3;
      *(ushort8*)(As + m * 40 + k8) =
          *(const ushort8*)(Ab + (size_t)(tm + m) * lda + k0 + k8);
    }
    if (BMODE == 0) {
      const float* Bf = (const float*)Bv;
      const int n = tid >> 2, k8 = (tid & 3) << 3;
      f32x4 x0 = *(const f32x4*)(Bf + (size_t)n * ldb + k0 + k8);
      f32x4 x1 = *(const f32x4*)(Bf + (size_t)n * ldb + k0 + k8 + 4);
      ushort8 o;
      o[0] = f2bf(x0[0]); o[1] = f2bf(x0[1]); o[2] = f2bf(x0[2]); o[3] = f2bf(x0[3]);
      o[4] = f2bf(x1[0]); o[5] = f2bf(x1[1]); o[6] = f2bf(x1[2]); o[7] = f2bf(x1[3]);
      *(ushort8*)(Bs + n * 40 + k8) = o;
    } else {
      const unsigned short* Bb = (const unsigned short*)Bv;
      const int n = tid >> 2, k8 = (tid & 3) << 3;
      *(ushort8*)(Bs + n * 40 + k8) =
          *(const ushort8*)(Bb + (size_t)n * ldb + k0 + k8);
    }
    __syncthreads();

    const int kr = (lane >> 4) << 3;
    short8 a = *(const short8*)(As + (w * 16 + (lane & 15)) * 40 + kr);
#pragma unroll
    for (int ni = 0; ni < 4; ni++) {
      short8 bb = *(const short8*)(Bs + (ni * 16 + (lane & 15)) * 40 + kr);
      acc[ni] = MFMA16B(a, bb, acc[ni]);
    }
    __syncthreads();
  }

  float* out = P + ((size_t)(br * KS + kz) * M) * 64;
#pragma unroll
  for (int ni = 0; ni < 4; ni++) {
    const int col = ni * 16 + (lane & 15);
#pragma unroll
    for (int r = 0; r < 4; r++) {
      const int row = tm + w * 16 + ((lane >> 4) << 2) + r;
      out[(size_t)row * 64 + col] = acc[ni][r];
    }
  }
}

// ---------------------------------------------------------------------------
template <int WF, int WB, int WT>
__global__ __launch_bounds__(256) void k_reduce(
    const float* __restrict__ P, size_t pbr_stride, float* F0, float* F1,
    unsigned short* Bo0, unsigned short* Bo1, unsigned short* T0,
    unsigned short* T1, int M, int KS, int ldT) {
  const int br = blockIdx.y;
  const float* Pp = P + (size_t)br * pbr_stride;
  const size_t i = (size_t)blockIdx.x * 256 + threadIdx.x;
  const size_t n = (size_t)M * 64;
  float s = 0.f;
  for (int k = 0; k < KS; k++) s += Pp[(size_t)k * n + i];
  if (WF) (br ? F1 : F0)[i] = s;
  if (WB) (br ? Bo1 : Bo0)[i] = f2bf(s);
  if (WT) {
    const int row = (int)(i >> 6), col = (int)(i & 63);
    (br ? T1 : T0)[(size_t)col * ldT + row] = f2bf(s);
  }
}

// ---------------------------------------------------------------------------
// Row softmax, single f32 slab per branch (z = branch): [2048,4096] -> bf16
// ---------------------------------------------------------------------------
__global__ __launch_bounds__(256) void k_softmax(
    const float* __restrict__ S, unsigned short* __restrict__ P0,
    unsigned short* __restrict__ P1, long slab) {
  const int row = blockIdx.x, br = blockIdx.y, tid = threadIdx.x;
  const float* s = S + (size_t)br * slab + (size_t)row * 4096;
  float v[16];
  float m = -1e30f;
#pragma unroll
  for (int j = 0; j < 16; j++) {
    v[j] = s[tid + j * 256];
    m = fmaxf(m, v[j]);
  }
  __shared__ float red[4], red2[4];
  for (int o = 32; o; o >>= 1) m = fmaxf(m, __shfl_down(m, o));
  if ((tid & 63) == 0) red[tid >> 6] = m;
  __syncthreads();
  m = fmaxf(fmaxf(red[0], red[1]), fmaxf(red[2], red[3]));
  float sum = 0.0f;
#pragma unroll
  for (int j = 0; j < 16; j++) {
    v[j] = expf(v[j] - m);
    sum += v[j];
  }
  for (int o = 32; o; o >>= 1) sum += __shfl_down(sum, o);
  if ((tid & 63) == 0) red2[tid >> 6] = sum;
  __syncthreads();
  const float inv = 1.0f / (red2[0] + red2[1] + red2[2] + red2[3]);
  unsigned short* p = (br ? P1 : P0) + (size_t)row * 4096;
#pragma unroll
  for (int j = 0; j < 16; j++) p[tid + j * 256] = f2bf(v[j] * inv);
}

// ---------------------------------------------------------------------------
__global__ __launch_bounds__(256) void k_user(
    const float* __restrict__ ue_mp, const float* __restrict__ ueat_mp,
    const float* __restrict__ ue_pmp, const float* __restrict__ ueat_pmp,
    const float* __restrict__ mlp_w, const float* __restrict__ mlp_b,
    const float* __restrict__ tr_w, const float* __restrict__ tr_b,
    float* __restrict__ out) {
  const int tid = threadIdx.x, d = tid & 63, w = tid >> 6;
  const int m = blockIdx.x * 4 + w;
  __shared__ float fus[4][64];
  float a1 = mlp_b[d], a2 = a1;
  const float* r1 = ue_mp + (size_t)m * 64;
  const float* r2 = ueat_mp + (size_t)m * 64;
  const float* r3 = ue_pmp + (size_t)m * 64;
  const float* r4 = ueat_pmp + (size_t)m * 64;
  const float* w1 = mlp_w + (size_t)d * 128;
#pragma unroll 8
  for (int k = 0; k < 64; k++) {
    const float wv = w1[k];
    a1 += r1[k] * wv;
    a2 += r3[k] * wv;
  }
#pragma unroll 8
  for (int k = 0; k < 64; k++) {
    const float wv = w1[64 + k];
    a1 += r2[k] * wv;
    a2 += r4[k] * wv;
  }
  const float u1 = sigmoidf_(a1), u2 = sigmoidf_(a2);
  const float rate = sigmoidf_(u1 + u2);
  fus[w][d] = rate * u1 + (1.0f - rate) * u2;
  __syncthreads();
  float o = tr_b[d];
  const float* tw = tr_w + (size_t)d * 64;
#pragma unroll 8
  for (int k = 0; k < 64; k++) o += fus[w][k] * tw[k];
  out[(size_t)m * 64 + d] = tanhf(o);
}

__global__ __launch_bounds__(256) void k_item(
    const float* __restrict__ ie_mp, const float* __restrict__ ie_pmp,
    const float* __restrict__ mlp_w, const float* __restrict__ mlp_b,
    float* __restrict__ out) {
  const int tid = threadIdx.x, d = tid & 63, w = tid >> 6;
  const int i = blockIdx.x * 4 + w;
  float a = mlp_b[d];
  const float* r1 = ie_mp + (size_t)i * 64;
  const float* r2 = ie_pmp + (size_t)i * 64;
  const float* wp = mlp_w + (size_t)d * 128;
#pragma unroll 8
  for (int k = 0; k < 64; k++) {
    a += r1[k] * wp[k];
    a += r2[k] * wp[64 + k];
  }
  out[(size_t)i * 64 + d] = sigmoidf_(a);
}

// ---------------------------------------------------------------------------
extern "C" void kernel_launch(void* const* d_in, const int* in_sizes, int n_in,
                              void* d_out, int out_size, void* d_ws,
                              size_t ws_size, hipStream_t stream) {
  const int U = 2048, I = 4096, D = 64, UI = 6144;
  const float WSC = 16.0f, DSC = 1.0f / 16.0f;

  const float* ui[2] = {(const float*)d_in[0], (const float*)d_in[1]};
  const float* Wu[2] = {(const float*)d_in[2], (const float*)d_in[3]};
  const float* Wi[2] = {(const float*)d_in[4], (const float*)d_in[5]};
  const float* mw[2] = {(const float*)d_in[6], (const float*)d_in[11]};
  const float* mb[2] = {(const float*)d_in[7], (const float*)d_in[12]};
  const float* aw[2] = {(const float*)d_in[8], (const float*)d_in[13]};
  const float* ab[2] = {(const float*)d_in[9], (const float*)d_in[14]};
  const float* Wat[2] = {(const float*)d_in[10], (const float*)d_in[15]};
  const float* mlp_w = (const float*)d_in[16];
  const float* mlp_b = (const float*)d_in[17];
  const float* tr_w = (const float*)d_in[18];
  const float* tr_b = (const float*)d_in[19];

  char* ws = (char*)d_ws;
  size_t off = 0;
  auto alloc = [&](size_t bytes) {
    void* p = ws + off;
    off += (bytes + 255) & ~(size_t)255;
    return p;
  };
  unsigned char* aw_f8[2] = {(unsigned char*)alloc((size_t)I * I),
                             (unsigned char*)alloc((size_t)I * I)};
  unsigned short* mw_bf[2] = {(unsigned short*)alloc((size_t)I * D * 2),
                              (unsigned short*)alloc((size_t)I * D * 2)};
  unsigned char* h_f8[2] = {(unsigned char*)alloc((size_t)UI * I),
                            (unsigned char*)alloc((size_t)UI * I)};
  unsigned char* aT_f8[2] = {(unsigned char*)alloc((size_t)I * UI),
                             (unsigned char*)alloc((size_t)I * UI)};
  float* scores = (float*)alloc((size_t)U * I * 4 * 2);  // 2 branch slabs
  unsigned short* at_bf[2] = {(unsigned short*)alloc((size_t)U * I * 2),
                              (unsigned short*)alloc((size_t)U * I * 2)};
  unsigned short* x_bf[2];
  float* ue_f[2];
  float* ie_f[2];
  unsigned short* ieT[2];
  float* ueat_f[2];
  for (int b = 0; b < 2; b++) {
    x_bf[b] = (unsigned short*)alloc((size_t)UI * D * 2);
    ue_f[b] = (float*)alloc((size_t)U * D * 4);
    ie_f[b] = (float*)alloc((size_t)I * D * 4);
    ieT[b] = (unsigned short*)alloc((size_t)D * I * 2);
    ueat_f[b] = (float*)alloc((size_t)U * D * 4);
  }
  // Lifetime aliases:
  //  pue (8.4MB)  -> h_f8[0] region (dead until h written)
  //  pie (16.8MB) -> aT_f8[0] region (dead until aT written)
  //  pueat (8.4MB)-> scores region (written after softmaxes read it)
  //  Wat_f8[b] (12.6MB) -> at_bf[b] region (written by softmax AFTER scores
  //  consumed Wat_f8 — stream-ordered, safe)
  float* pue = (float*)h_f8[0];
  float* pie = (float*)aT_f8[0];
  float* pueat = scores;
  unsigned char* Wat_f8[2] = {(unsigned char*)at_bf[0],
                              (unsigned char*)at_bf[1]};
  const long zsf = (long)U * I;

  const dim3 blk(256);

  // ue: [U,64] over K=I, both branches, KS=8
  k_sgemm64s<0, 0><<<dim3(U / 64, 8, 2), blk, 0, stream>>>(
      ui[0], ui[1], Wu[0], Wu[1], pue, I / 8, I, I, U);
  k_reduce<1, 1, 0><<<dim3(U * 64 / 256, 2), blk, 0, stream>>>(
      pue, (size_t)8 * U * 64, ue_f[0], ue_f[1], x_bf[0], x_bf[1], nullptr,
      nullptr, U, 8, 0);
  // ie: [I,64] over K=U (A = ui^T), both branches, KS=8
  k_sgemm64s<1, 0><<<dim3(I / 64, 8, 2), blk, 0, stream>>>(
      ui[0], ui[1], Wi[0], Wi[1], pie, U / 8, I, U, I);
  k_reduce<1, 1, 1><<<dim3(I * 64 / 256, 2), blk, 0, stream>>>(
      pie, (size_t)8 * I * 64, ie_f[0], ie_f[1], x_bf[0] + (size_t)U * D,
      x_bf[1] + (size_t)U * D, ieT[0], ieT[1], I, 8, I);

  // converts (all weights, both branches)
  for (int b = 0; b < 2; b++) {
    k_f32_to_fp8<<<2048, blk, 0, stream>>>(aw[b], aw_f8[b], (long)I * I, WSC);
    k_f32_to_fp8<<<2048, blk, 0, stream>>>(Wat[b], Wat_f8[b], (long)U * UI, WSC);
    k_f32_to_bf16<<<128, blk, 0, stream>>>(mw[b], mw_bf[b], (long)I * D);
  }

  // h both branches: [6144,4096], K=64 (z = branch)
  k_gemmH<<<dim3(UI / 128, I / 128, 2), blk, 0, stream>>>(
      x_bf[0], x_bf[1], mw_bf[0], mw_bf[1], h_f8[0], h_f8[1], mb[0], mb[1],
      UI, I, D);

  // aT both branches: [4096,6144], K=4096; 768 blocks = 3 exact rounds
  k_gemmMX<1><<<dim3(I / 256, UI / 256, 2), dim3(512), 0, stream>>>(
      aw_f8[0], aw_f8[1], h_f8[0], h_f8[1], nullptr, aT_f8[0], aT_f8[1],
      ab[0], ab[1], I, UI, I, 0, DSC);

  // scores both branches: [2048,4096], K=6144; 256 blocks = 1 exact round
  k_gemmMX<0><<<dim3(U / 256, I / 256, 2), dim3(512), 0, stream>>>(
      Wat_f8[0], Wat_f8[1], aT_f8[0], aT_f8[1], scores, nullptr, nullptr,
      nullptr, nullptr, U, I, UI, zsf, DSC);

  // softmax both branches (clobbers Wat_f8 alias — Wat dead after scores)
  k_softmax<<<dim3(U, 2), blk, 0, stream>>>(scores, at_bf[0], at_bf[1], zsf);

  // ue_at both branches: [U,64] over K=I, KS=8
  k_sgemm64s<2, 2><<<dim3(U / 64, 8, 2), blk, 0, stream>>>(
      at_bf[0], at_bf[1], ieT[0], ieT[1], pueat, I / 8, I, I, U);
  k_reduce<1, 0, 0><<<dim3(U * 64 / 256, 2), blk, 0, stream>>>(
      pueat, (size_t)8 * U * 64, ueat_f[0], ueat_f[1], nullptr, nullptr,
      nullptr, nullptr, U, 8, 0);

  float* out_user = (float*)d_out;
  float* out_item = (float*)d_out + (size_t)U * D;
  k_user<<<U / 4, blk, 0, stream>>>(ue_f[0], ueat_f[0], ue_f[1], ueat_f[1],
                                    mlp_w, mlp_b, tr_w, tr_b, out_user);
  k_item<<<I / 4, blk, 0, stream>>>(ie_f[0], ie_f[1], mlp_w, mlp_b, out_item);
}

// Round 14
// 601.983 us; speedup vs baseline: 1.2223x; 1.1861x over previous
//
#include <hip/hip_runtime.h>
#include <stdint.h>
#include <math.h>

// ---------------------------------------------------------------------------
// PAAE layer, MI355X (gfx950). Round 14: 256^2 MX-fp8 GEMM, spill-free inner
// loop. R13 arithmetic: 128KB LDS -> 1 blk/CU -> 2 waves/SIMD -> 256 regs =
// 128 AGPR (acc) + 128 VGPR cap; batched operand reads kept ~96-128 temps
// live -> spill (WRITE_SIZE 94MB vs 49). Fix: read bf[0..3] once (32 regs),
// then per mi: read ONE a-frag (8 regs) -> 4 MFMAs immediately. Peak operand
// pressure ~56 regs. Everything else identical to R13.
// ---------------------------------------------------------------------------

typedef short short8 __attribute__((ext_vector_type(8)));
typedef unsigned short ushort8 __attribute__((ext_vector_type(8)));
typedef unsigned char uchar8 __attribute__((ext_vector_type(8)));
typedef float f32x4 __attribute__((ext_vector_type(4)));
typedef int int4v __attribute__((ext_vector_type(4)));
typedef int int8v __attribute__((ext_vector_type(8)));

#define DEVI static __device__ __forceinline__

DEVI unsigned short f2bf(float f) {  // RNE float -> bf16 bits
  uint32_t u = __builtin_bit_cast(uint32_t, f);
  return (unsigned short)((u + 0x7fffu + ((u >> 16) & 1u)) >> 16);
}
DEVI unsigned char f2fp8(float f) {  // RNE float -> OCP e4m3fn
  uint32_t u = __builtin_bit_cast(uint32_t, f);
  uint32_t s = (u >> 24) & 0x80u;
  uint32_t a = u & 0x7fffffffu;
  if (a >= 0x43e00000u) return (unsigned char)(s | 0x7eu);  // sat to 448
  if (a < 0x3c800000u) {  // |f| < 2^-6 -> subnormal, step 2^-9
    float af = __builtin_bit_cast(float, a);
    uint32_t n = (uint32_t)__builtin_rintf(af * 512.0f);
    return (unsigned char)(s | n);
  }
  uint32_t r = a + 0xfffffu + ((a >> 20) & 1u);
  return (unsigned char)(s | ((r >> 20) - 960u));
}
DEVI float sigmoidf_(float x) { return 1.0f / (1.0f + expf(-x)); }

DEVI void gld16(const void* g, void* l) {
  __builtin_amdgcn_global_load_lds(
      (const __attribute__((address_space(1))) unsigned int*)g,
      (__attribute__((address_space(3))) unsigned int*)l, 16, 0, 0);
}

#define MFMA16B(a, b, c) __builtin_amdgcn_mfma_f32_16x16x32_bf16(a, b, c, 0, 0, 0)
#define MFMAMX(a, b, c)                                              \
  __builtin_amdgcn_mfma_scale_f32_16x16x128_f8f6f4(                  \
      a, b, c, 0, 0, 0, 0x7f7f7f7fu, 0, 0x7f7f7f7fu)

// ---------------------------------------------------------------------------
__global__ __launch_bounds__(256) void k_f32_to_bf16(
    const float* __restrict__ s, unsigned short* __restrict__ d, long n) {
  long i0 = ((long)blockIdx.x * 256 + threadIdx.x) * 8;
  long stride = (long)gridDim.x * 256 * 8;
  for (long i = i0; i < n; i += stride) {
    f32x4 a = *(const f32x4*)(s + i);
    f32x4 b = *(const f32x4*)(s + i + 4);
    ushort8 o;
    o[0] = f2bf(a[0]); o[1] = f2bf(a[1]); o[2] = f2bf(a[2]); o[3] = f2bf(a[3]);
    o[4] = f2bf(b[0]); o[5] = f2bf(b[1]); o[6] = f2bf(b[2]); o[7] = f2bf(b[3]);
    *(ushort8*)(d + i) = o;
  }
}

__global__ __launch_bounds__(256) void k_f32_to_fp8(
    const float* __restrict__ s, unsigned char* __restrict__ d, long n,
    float scale) {
  long i0 = ((long)blockIdx.x * 256 + threadIdx.x) * 8;
  long stride = (long)gridDim.x * 256 * 8;
  for (long i = i0; i < n; i += stride) {
    f32x4 a = *(const f32x4*)(s + i);
    f32x4 b = *(const f32x4*)(s + i + 4);
    uchar8 o;
    o[0] = f2fp8(a[0] * scale); o[1] = f2fp8(a[1] * scale);
    o[2] = f2fp8(a[2] * scale); o[3] = f2fp8(a[3] * scale);
    o[4] = f2fp8(b[0] * scale); o[5] = f2fp8(b[1] * scale);
    o[6] = f2fp8(b[2] * scale); o[7] = f2fp8(b[3] * scale);
    *(uchar8*)(d + i) = o;
  }
}

// ---------------------------------------------------------------------------
// MX-fp8 GEMM, 256x256 tile, BK=128, 8 waves, double-buffered 128KB LDS.
// C[M,N] = A[M,K]*B[N,K]^T, A/B e4m3 row-major, K%256==0.
// Flat LDS: buf base 0/65536; op base +0 (A) / +32768 (B). Row = 128 B
// (8 chunks of 16B); chunk c stored at c^(row&7) via inverse-swizzled global
// source (linear gld16 dest); frag reads XOR the same.
// Frag (16x16x128): lane l: row=l&15, k=(l>>4)*32+0..31 (2 b128 chunks).
// Waves: wr=wid>>2 (128 rows), wc=wid&3 (64 cols).
// Inner loop: bf[0..3] resident; per mi one a-frag then 4 MFMAs (anti-spill).
// EPI 0: outF[z*zsf + row*N + col] = acc*dsc   (z = branch)
// EPI 1: outB[z] = e4m3(tanh(acc*dsc + bias[row]))
// ---------------------------------------------------------------------------
template <int EPI>
__global__ __launch_bounds__(512, 1) void k_gemmMX(
    const unsigned char* __restrict__ A0, const unsigned char* __restrict__ A1,
    const unsigned char* __restrict__ B0, const unsigned char* __restrict__ B1,
    float* __restrict__ outF, unsigned char* __restrict__ oB0,
    unsigned char* __restrict__ oB1, const float* __restrict__ bias0,
    const float* __restrict__ bias1, int M, int N, int K, long zsf,
    float dsc) {
  // XCD-aware bijective swizzle of the xy-plane (plane size % 8 == 0)
  const int gx = gridDim.x;
  const int nwg = gx * gridDim.y;
  const int flat = blockIdx.y * gx + blockIdx.x;
  const int swz = (flat & 7) * (nwg >> 3) + (flat >> 3);
  const int bxi = swz % gx, byi = swz / gx;

  const int bz = blockIdx.z;
  const unsigned char* A = bz ? A1 : A0;
  const unsigned char* B = bz ? B1 : B0;
  unsigned char* outB = bz ? oB1 : oB0;
  const float* bias = bz ? bias1 : bias0;

  __shared__ unsigned char lds[131072];
  const int tid = threadIdx.x, lane = tid & 63;
  const int wid = tid >> 6, wr = wid >> 2, wc = wid & 3;
  const int bm = bxi * 256, bn = byi * 256;
  const int rl = lane & 15, q = lane >> 4;

  // fragment read offsets: two b128 chunks per 32B fragment
  const int x7 = rl & 7;
  const int c0 = ((2 * q) ^ x7) << 4;
  const int c1 = ((2 * q + 1) ^ x7) << 4;

  const unsigned char* gA = A + (size_t)bm * K;
  const unsigned char* gB = B + (size_t)bn * K;

  // bufb: literal 0 or 65536. Addressing rematerialized from tid (anti-spill).
  auto stage = [&](int kc, int bufb) {
#pragma unroll
    for (int i = 0; i < 4; i++) {
      const int cid = tid + 512 * i;
      const int r = cid >> 3;
      const int go = r * K + (((cid & 7) ^ (r & 7)) << 4) + kc;  // < 2^31
      const int dst = cid << 4;
      gld16(gA + go, &lds[bufb + dst]);
      gld16(gB + go, &lds[bufb + 32768 + dst]);
    }
  };

  f32x4 acc[8][4] = {};

  auto frag = [&](const unsigned char* p) {
    int4v lo = *(const int4v*)(p + c0);
    int4v hi = *(const int4v*)(p + c1);
    return __builtin_shufflevector(lo, hi, 0, 1, 2, 3, 4, 5, 6, 7);
  };

  // one K-tile: compute from literal buf base cb, prefetch kc+128 into pb
  auto body = [&](int kc, int cb, int pb) {
    if (kc + 128 < K) stage(kc + 128, pb);

    const unsigned char* As = lds + cb + wr * 16384;        // wave's 128 rows
    const unsigned char* Bs = lds + cb + 32768 + wc * 8192; // wave's 64 rows

    int8v bf[4];
#pragma unroll
    for (int nf = 0; nf < 4; nf++) bf[nf] = frag(Bs + (nf * 16 + rl) * 128);

    __builtin_amdgcn_s_setprio(1);
#pragma unroll
    for (int mi = 0; mi < 8; mi++) {
      int8v a = frag(As + (mi * 16 + rl) * 128);
#pragma unroll
      for (int nf = 0; nf < 4; nf++)
        acc[mi][nf] = MFMAMX(a, bf[nf], acc[mi][nf]);
    }
    __builtin_amdgcn_s_setprio(0);

    if (kc + 128 < K) {
      // next tile staged + all waves done reading buf cb
      asm volatile("s_waitcnt vmcnt(0)\ns_barrier" ::: "memory");
    }
  };

  stage(0, 0);
  asm volatile("s_waitcnt vmcnt(0)\ns_barrier" ::: "memory");

  for (int k0 = 0; k0 < K; k0 += 256) {
    body(k0, 0, 65536);
    body(k0 + 128, 65536, 0);
  }

#pragma unroll
  for (int m = 0; m < 8; m++) {
#pragma unroll
    for (int nf = 0; nf < 4; nf++) {
      const int col = bn + wc * 64 + nf * 16 + rl;
#pragma unroll
      for (int r = 0; r < 4; r++) {
        const int row = bm + wr * 128 + m * 16 + q * 4 + r;
        const float v = acc[m][nf][r] * dsc;
        if (EPI == 0)
          outF[(long)bz * zsf + (size_t)row * N + col] = v;
        else
          outB[(size_t)row * N + col] = f2fp8(tanhf(v + bias[row]));
      }
    }
  }
}

// ---------------------------------------------------------------------------
// h = e4m3(tanh(relu(x @ mw^T + mb))), fused over branches (z = branch).
// ---------------------------------------------------------------------------
__global__ __launch_bounds__(256) void k_gemmH(
    const unsigned short* __restrict__ A0, const unsigned short* __restrict__ A1,
    const unsigned short* __restrict__ B0, const unsigned short* __restrict__ B1,
    unsigned char* __restrict__ o0, unsigned char* __restrict__ o1,
    const float* __restrict__ bias0, const float* __restrict__ bias1, int M,
    int N, int K) {
  const int bz = blockIdx.z;
  const unsigned short* A = bz ? A1 : A0;
  const unsigned short* B = bz ? B1 : B0;
  unsigned char* out8 = bz ? o1 : o0;
  const float* bias = bz ? bias1 : bias0;

  __shared__ unsigned short As[128 * 32];
  __shared__ unsigned short Bs[128 * 32];
  const int tid = threadIdx.x, lane = tid & 63, wid = tid >> 6;
  const int wr = wid >> 1, wc = wid & 1;
  const int bm = blockIdx.x * 128, bn = blockIdx.y * 128;
  const int c0 = tid, c1 = tid + 256;
  const int s0 = ((c0 & 3) ^ ((c0 >> 3) & 3)) << 3;
  const int s1 = ((c1 & 3) ^ ((c1 >> 3) & 3)) << 3;
  const int rl = lane & 15, q = lane >> 4;
  const int qe = (q ^ ((rl >> 1) & 3)) << 3;

  f32x4 acc[4][4] = {};

  for (int k0 = 0; k0 < K; k0 += 32) {
    gld16(A + (size_t)(bm + (c0 >> 2)) * K + k0 + s0, As + c0 * 8);
    gld16(A + (size_t)(bm + (c1 >> 2)) * K + k0 + s1, As + c1 * 8);
    gld16(B + (size_t)(bn + (c0 >> 2)) * K + k0 + s0, Bs + c0 * 8);
    gld16(B + (size_t)(bn + (c1 >> 2)) * K + k0 + s1, Bs + c1 * 8);
    __syncthreads();

    short8 af[4], bfr[4];
#pragma unroll
    for (int mi = 0; mi < 4; mi++)
      af[mi] = *(const short8*)(As + (wr * 64 + mi * 16 + rl) * 32 + qe);
#pragma unroll
    for (int ni = 0; ni < 4; ni++)
      bfr[ni] = *(const short8*)(Bs + (wc * 64 + ni * 16 + rl) * 32 + qe);
#pragma unroll
    for (int mi = 0; mi < 4; mi++)
#pragma unroll
      for (int ni = 0; ni < 4; ni++)
        acc[mi][ni] = MFMA16B(af[mi], bfr[ni], acc[mi][ni]);
    __syncthreads();
  }

#pragma unroll
  for (int mi = 0; mi < 4; mi++) {
#pragma unroll
    for (int ni = 0; ni < 4; ni++) {
      const int col = bn + wc * 64 + ni * 16 + rl;
#pragma unroll
      for (int r = 0; r < 4; r++) {
        const int row = bm + wr * 64 + mi * 16 + q * 4 + r;
        out8[(size_t)row * N + col] =
            f2fp8(tanhf(fmaxf(acc[mi][ni][r] + bias[col], 0.0f)));
      }
    }
  }
}

// ---------------------------------------------------------------------------
// Skinny GEMM, N=64, split-K. grid: (M/64, KS, nbr)
// ---------------------------------------------------------------------------
template <int AMODE, int BMODE>
__global__ __launch_bounds__(256) void k_sgemm64s(
    const void* __restrict__ A0, const void* __restrict__ A1,
    const void* __restrict__ B0, const void* __restrict__ B1,
    float* __restrict__ P, int kchunk, int lda, int ldb, int M) {
  const int br = blockIdx.z, kz = blockIdx.y, KS = gridDim.y;
  const void* Av = br ? A1 : A0;
  const void* Bv = br ? B1 : B0;

  __shared__ unsigned short As[64 * 40];
  __shared__ unsigned short Bs[64 * 40];
  const int tid = threadIdx.x, lane = tid & 63, w = tid >> 6;
  const int tm = blockIdx.x * 64;

  f32x4 acc[4] = {};
  const int kbeg = kz * kchunk, kend = kbeg + kchunk;

  for (int k0 = kbeg; k0 < kend; k0 += 32) {
    if (AMODE == 0) {
      const float* Af = (const float*)Av;
      const int m = tid >> 2, k8 = (tid & 3) << 3;
      f32x4 x0 = *(const f32x4*)(Af + (size_t)(tm + m) * lda + k0 + k8);
      f32x4 x1 = *(const f32x4*)(Af + (size_t)(tm + m) * lda + k0 + k8 + 4);
      ushort8 o;
      o[0] = f2bf(x0[0]); o[1] = f2bf(x0[1]); o[2] = f2bf(x0[2]); o[3] = f2bf(x0[3]);
      o[4] = f2bf(x1[0]); o[5] = f2bf(x1[1]); o[6] = f2bf(x1[2]); o[7] = f2bf(x1[3]);
      *(ushort8*)(As + m * 40 + k8) = o;
    } else if (AMODE == 1) {
      const float* Af = (const float*)Av;
#pragma unroll
      for (int t = 0; t < 2; t++) {
        const int c = tid + t * 256;
        const int u = c >> 4, i4 = (c & 15) << 2;
        f32x4 x = *(const f32x4*)(Af + (size_t)(k0 + u) * lda + tm + i4);
        As[(i4 + 0) * 40 + u] = f2bf(x[0]);
        As[(i4 + 1) * 40 + u] = f2bf(x[1]);
        As[(i4 + 2) * 40 + u] = f2bf(x[2]);
        As[(i4 + 3) * 40 + u] = f2bf(x[3]);
      }
    } else {
      const unsigned short* Ab = (const unsigned short*)Av;
      const int m = tid >> 2, k8 = (tid & 3) << 3;
      *(ushort8*)(As + m * 40 + k8) =
          *(const ushort8*)(Ab + (size_t)(tm + m) * lda + k0 + k8);
    }
    if (BMODE == 0) {
      const float* Bf = (const float*)Bv;
      const int n = tid >> 2, k8 = (tid & 3) << 3;
      f32x4 x0 = *(const f32x4*)(Bf + (size_t)n * ldb + k0 + k8);
      f32x4 x1 = *(const f32x4*)(Bf + (size_t)n * ldb + k0 + k8 + 4);
      ushort8 o;
      o[0] = f2bf(x0[0]); o[1] = f2bf(x0[1]); o[2] = f2bf(x0[2]); o[3] = f2bf(x0[3]);
      o[4] = f2bf(x1[0]); o[5] = f2bf(x1[1]); o[6] = f2bf(x1[2]); o[7] = f2bf(x1[3]);
      *(ushort8*)(Bs + n * 40 + k8) = o;
    } else {
      const unsigned short* Bb = (const unsigned short*)Bv;
      const int n = tid >> 2, k8 = (tid & 3) << 3;
      *(ushort8*)(Bs + n * 40 + k8) =
          *(const ushort8*)(Bb + (size_t)n * ldb + k0 + k8);
    }
    __syncthreads();

    const int kr = (lane >> 4) << 3;
    short8 a = *(const short8*)(As + (w * 16 + (lane & 15)) * 40 + kr);
#pragma unroll
    for (int ni = 0; ni < 4; ni++) {
      short8 bb = *(const short8*)(Bs + (ni * 16 + (lane & 15)) * 40 + kr);
      acc[ni] = MFMA16B(a, bb, acc[ni]);
    }
    __syncthreads();
  }

  float* out = P + ((size_t)(br * KS + kz) * M) * 64;
#pragma unroll
  for (int ni = 0; ni < 4; ni++) {
    const int col = ni * 16 + (lane & 15);
#pragma unroll
    for (int r = 0; r < 4; r++) {
      const int row = tm + w * 16 + ((lane >> 4) << 2) + r;
      out[(size_t)row * 64 + col] = acc[ni][r];
    }
  }
}

// ---------------------------------------------------------------------------
template <int WF, int WB, int WT>
__global__ __launch_bounds__(256) void k_reduce(
    const float* __restrict__ P, size_t pbr_stride, float* F0, float* F1,
    unsigned short* Bo0, unsigned short* Bo1, unsigned short* T0,
    unsigned short* T1, int M, int KS, int ldT) {
  const int br = blockIdx.y;
  const float* Pp = P + (size_t)br * pbr_stride;
  const size_t i = (size_t)blockIdx.x * 256 + threadIdx.x;
  const size_t n = (size_t)M * 64;
  float s = 0.f;
  for (int k = 0; k < KS; k++) s += Pp[(size_t)k * n + i];
  if (WF) (br ? F1 : F0)[i] = s;
  if (WB) (br ? Bo1 : Bo0)[i] = f2bf(s);
  if (WT) {
    const int row = (int)(i >> 6), col = (int)(i & 63);
    (br ? T1 : T0)[(size_t)col * ldT + row] = f2bf(s);
  }
}

// ---------------------------------------------------------------------------
// Row softmax, single f32 slab per branch (z = branch): [2048,4096] -> bf16
// ---------------------------------------------------------------------------
__global__ __launch_bounds__(256) void k_softmax(
    const float* __restrict__ S, unsigned short* __restrict__ P0,
    unsigned short* __restrict__ P1, long slab) {
  const int row = blockIdx.x, br = blockIdx.y, tid = threadIdx.x;
  const float* s = S + (size_t)br * slab + (size_t)row * 4096;
  float v[16];
  float m = -1e30f;
#pragma unroll
  for (int j = 0; j < 16; j++) {
    v[j] = s[tid + j * 256];
    m = fmaxf(m, v[j]);
  }
  __shared__ float red[4], red2[4];
  for (int o = 32; o; o >>= 1) m = fmaxf(m, __shfl_down(m, o));
  if ((tid & 63) == 0) red[tid >> 6] = m;
  __syncthreads();
  m = fmaxf(fmaxf(red[0], red[1]), fmaxf(red[2], red[3]));
  float sum = 0.0f;
#pragma unroll
  for (int j = 0; j < 16; j++) {
    v[j] = expf(v[j] - m);
    sum += v[j];
  }
  for (int o = 32; o; o >>= 1) sum += __shfl_down(sum, o);
  if ((tid & 63) == 0) red2[tid >> 6] = sum;
  __syncthreads();
  const float inv = 1.0f / (red2[0] + red2[1] + red2[2] + red2[3]);
  unsigned short* p = (br ? P1 : P0) + (size_t)row * 4096;
#pragma unroll
  for (int j = 0; j < 16; j++) p[tid + j * 256] = f2bf(v[j] * inv);
}

// ---------------------------------------------------------------------------
__global__ __launch_bounds__(256) void k_user(
    const float* __restrict__ ue_mp, const float* __restrict__ ueat_mp,
    const float* __restrict__ ue_pmp, const float* __restrict__ ueat_pmp,
    const float* __restrict__ mlp_w, const float* __restrict__ mlp_b,
    const float* __restrict__ tr_w, const float* __restrict__ tr_b,
    float* __restrict__ out) {
  const int tid = threadIdx.x, d = tid & 63, w = tid >> 6;
  const int m = blockIdx.x * 4 + w;
  __shared__ float fus[4][64];
  float a1 = mlp_b[d], a2 = a1;
  const float* r1 = ue_mp + (size_t)m * 64;
  const float* r2 = ueat_mp + (size_t)m * 64;
  const float* r3 = ue_pmp + (size_t)m * 64;
  const float* r4 = ueat_pmp + (size_t)m * 64;
  const float* w1 = mlp_w + (size_t)d * 128;
#pragma unroll 8
  for (int k = 0; k < 64; k++) {
    const float wv = w1[k];
    a1 += r1[k] * wv;
    a2 += r3[k] * wv;
  }
#pragma unroll 8
  for (int k = 0; k < 64; k++) {
    const float wv = w1[64 + k];
    a1 += r2[k] * wv;
    a2 += r4[k] * wv;
  }
  const float u1 = sigmoidf_(a1), u2 = sigmoidf_(a2);
  const float rate = sigmoidf_(u1 + u2);
  fus[w][d] = rate * u1 + (1.0f - rate) * u2;
  __syncthreads();
  float o = tr_b[d];
  const float* tw = tr_w + (size_t)d * 64;
#pragma unroll 8
  for (int k = 0; k < 64; k++) o += fus[w][k] * tw[k];
  out[(size_t)m * 64 + d] = tanhf(o);
}

__global__ __launch_bounds__(256) void k_item(
    const float* __restrict__ ie_mp, const float* __restrict__ ie_pmp,
    const float* __restrict__ mlp_w, const float* __restrict__ mlp_b,
    float* __restrict__ out) {
  const int tid = threadIdx.x, d = tid & 63, w = tid >> 6;
  const int i = blockIdx.x * 4 + w;
  float a = mlp_b[d];
  const float* r1 = ie_mp + (size_t)i * 64;
  const float* r2 = ie_pmp + (size_t)i * 64;
  const float* wp = mlp_w + (size_t)d * 128;
#pragma unroll 8
  for (int k = 0; k < 64; k++) {
    a += r1[k] * wp[k];
    a += r2[k] * wp[64 + k];
  }
  out[(size_t)i * 64 + d] = sigmoidf_(a);
}

// ---------------------------------------------------------------------------
extern "C" void kernel_launch(void* const* d_in, const int* in_sizes, int n_in,
                              void* d_out, int out_size, void* d_ws,
                              size_t ws_size, hipStream_t stream) {
  const int U = 2048, I = 4096, D = 64, UI = 6144;
  const float WSC = 16.0f, DSC = 1.0f / 16.0f;

  const float* ui[2] = {(const float*)d_in[0], (const float*)d_in[1]};
  const float* Wu[2] = {(const float*)d_in[2], (const float*)d_in[3]};
  const float* Wi[2] = {(const float*)d_in[4], (const float*)d_in[5]};
  const float* mw[2] = {(const float*)d_in[6], (const float*)d_in[11]};
  const float* mb[2] = {(const float*)d_in[7], (const float*)d_in[12]};
  const float* aw[2] = {(const float*)d_in[8], (const float*)d_in[13]};
  const float* ab[2] = {(const float*)d_in[9], (const float*)d_in[14]};
  const float* Wat[2] = {(const float*)d_in[10], (const float*)d_in[15]};
  const float* mlp_w = (const float*)d_in[16];
  const float* mlp_b = (const float*)d_in[17];
  const float* tr_w = (const float*)d_in[18];
  const float* tr_b = (const float*)d_in[19];

  char* ws = (char*)d_ws;
  size_t off = 0;
  auto alloc = [&](size_t bytes) {
    void* p = ws + off;
    off += (bytes + 255) & ~(size_t)255;
    return p;
  };
  unsigned char* aw_f8[2] = {(unsigned char*)alloc((size_t)I * I),
                             (unsigned char*)alloc((size_t)I * I)};
  unsigned short* mw_bf[2] = {(unsigned short*)alloc((size_t)I * D * 2),
                              (unsigned short*)alloc((size_t)I * D * 2)};
  unsigned char* h_f8[2] = {(unsigned char*)alloc((size_t)UI * I),
                            (unsigned char*)alloc((size_t)UI * I)};
  unsigned char* aT_f8[2] = {(unsigned char*)alloc((size_t)I * UI),
                             (unsigned char*)alloc((size_t)I * UI)};
  float* scores = (float*)alloc((size_t)U * I * 4 * 2);  // 2 branch slabs
  unsigned short* at_bf[2] = {(unsigned short*)alloc((size_t)U * I * 2),
                              (unsigned short*)alloc((size_t)U * I * 2)};
  unsigned short* x_bf[2];
  float* ue_f[2];
  float* ie_f[2];
  unsigned short* ieT[2];
  float* ueat_f[2];
  for (int b = 0; b < 2; b++) {
    x_bf[b] = (unsigned short*)alloc((size_t)UI * D * 2);
    ue_f[b] = (float*)alloc((size_t)U * D * 4);
    ie_f[b] = (float*)alloc((size_t)I * D * 4);
    ieT[b] = (unsigned short*)alloc((size_t)D * I * 2);
    ueat_f[b] = (float*)alloc((size_t)U * D * 4);
  }
  // Lifetime aliases:
  //  pue (8.4MB)  -> h_f8[0] region (dead until h written)
  //  pie (16.8MB) -> aT_f8[0] region (dead until aT written)
  //  pueat (8.4MB)-> scores region (written after softmaxes read it)
  //  Wat_f8[b] (12.6MB) -> at_bf[b] region (written by softmax AFTER scores
  //  consumed Wat_f8 — stream-ordered, safe)
  float* pue = (float*)h_f8[0];
  float* pie = (float*)aT_f8[0];
  float* pueat = scores;
  unsigned char* Wat_f8[2] = {(unsigned char*)at_bf[0],
                              (unsigned char*)at_bf[1]};
  const long zsf = (long)U * I;

  const dim3 blk(256);

  // ue: [U,64] over K=I, both branches, KS=8
  k_sgemm64s<0, 0><<<dim3(U / 64, 8, 2), blk, 0, stream>>>(
      ui[0], ui[1], Wu[0], Wu[1], pue, I / 8, I, I, U);
  k_reduce<1, 1, 0><<<dim3(U * 64 / 256, 2), blk, 0, stream>>>(
      pue, (size_t)8 * U * 64, ue_f[0], ue_f[1], x_bf[0], x_bf[1], nullptr,
      nullptr, U, 8, 0);
  // ie: [I,64] over K=U (A = ui^T), both branches, KS=8
  k_sgemm64s<1, 0><<<dim3(I / 64, 8, 2), blk, 0, stream>>>(
      ui[0], ui[1], Wi[0], Wi[1], pie, U / 8, I, U, I);
  k_reduce<1, 1, 1><<<dim3(I * 64 / 256, 2), blk, 0, stream>>>(
      pie, (size_t)8 * I * 64, ie_f[0], ie_f[1], x_bf[0] + (size_t)U * D,
      x_bf[1] + (size_t)U * D, ieT[0], ieT[1], I, 8, I);

  // converts (all weights, both branches)
  for (int b = 0; b < 2; b++) {
    k_f32_to_fp8<<<2048, blk, 0, stream>>>(aw[b], aw_f8[b], (long)I * I, WSC);
    k_f32_to_fp8<<<2048, blk, 0, stream>>>(Wat[b], Wat_f8[b], (long)U * UI, WSC);
    k_f32_to_bf16<<<128, blk, 0, stream>>>(mw[b], mw_bf[b], (long)I * D);
  }

  // h both branches: [6144,4096], K=64 (z = branch)
  k_gemmH<<<dim3(UI / 128, I / 128, 2), blk, 0, stream>>>(
      x_bf[0], x_bf[1], mw_bf[0], mw_bf[1], h_f8[0], h_f8[1], mb[0], mb[1],
      UI, I, D);

  // aT both branches: [4096,6144], K=4096; 768 blocks = 3 exact rounds
  k_gemmMX<1><<<dim3(I / 256, UI / 256, 2), dim3(512), 0, stream>>>(
      aw_f8[0], aw_f8[1], h_f8[0], h_f8[1], nullptr, aT_f8[0], aT_f8[1],
      ab[0], ab[1], I, UI, I, 0, DSC);

  // scores both branches: [2048,4096], K=6144; 256 blocks = 1 exact round
  k_gemmMX<0><<<dim3(U / 256, I / 256, 2), dim3(512), 0, stream>>>(
      Wat_f8[0], Wat_f8[1], aT_f8[0], aT_f8[1], scores, nullptr, nullptr,
      nullptr, nullptr, U, I, UI, zsf, DSC);

  // softmax both branches (clobbers Wat_f8 alias — Wat dead after scores)
  k_softmax<<<dim3(U, 2), blk, 0, stream>>>(scores, at_bf[0], at_bf[1], zsf);

  // ue_at both branches: [U,64] over K=I, KS=8
  k_sgemm64s<2, 2><<<dim3(U / 64, 8, 2), blk, 0, stream>>>(
      at_bf[0], at_bf[1], ieT[0], ieT[1], pueat, I / 8, I, I, U);
  k_reduce<1, 0, 0><<<dim3(U * 64 / 256, 2), blk, 0, stream>>>(
      pueat, (size_t)8 * U * 64, ueat_f[0], ueat_f[1], nullptr, nullptr,
      nullptr, nullptr, U, 8, 0);

  float* out_user = (float*)d_out;
  float* out_item = (float*)d_out + (size_t)U * D;
  k_user<<<U / 4, blk, 0, stream>>>(ue_f[0], ueat_f[0], ue_f[1], ueat_f[1],
                                    mlp_w, mlp_b, tr_w, tr_b, out_user);
  k_item<<<I / 4, blk, 0, stream>>>(ie_f[0], ie_f[1], mlp_w, mlp_b, out_item);
}

// Round 15
// 576.135 us; speedup vs baseline: 1.2772x; 1.0449x over previous
//
#include <hip/hip_runtime.h>
#include <stdint.h>
#include <math.h>

// ---------------------------------------------------------------------------
// PAAE layer, MI355X (gfx950). Round 15: 256x128 MX-fp8 GEMM @ 2 blocks/CU.
// R14 audit: 256^2 shape is register-pinned to 1 block/CU -> no cross-block
// overlap -> 34% of pipe floor; R10/R11 (2 blocks/CU) hit ~74%. New geometry:
// tile 256x128, 8 waves (wave-tile 64x64, acc=64 AGPR), single-buffered 48KB
// LDS, __launch_bounds__(512,4) caps 128 regs/wave -> 16 waves/CU = 2 blocks.
// R10's proven protocol: stage -> vmcnt(0)+barrier -> compute -> barrier.
// Grids: aT (16,48,2)=1536 (3 exact super-rounds), scores (8,32,2)=512.
// ---------------------------------------------------------------------------

typedef short short8 __attribute__((ext_vector_type(8)));
typedef unsigned short ushort8 __attribute__((ext_vector_type(8)));
typedef unsigned char uchar8 __attribute__((ext_vector_type(8)));
typedef float f32x4 __attribute__((ext_vector_type(4)));
typedef int int4v __attribute__((ext_vector_type(4)));
typedef int int8v __attribute__((ext_vector_type(8)));

#define DEVI static __device__ __forceinline__

DEVI unsigned short f2bf(float f) {  // RNE float -> bf16 bits
  uint32_t u = __builtin_bit_cast(uint32_t, f);
  return (unsigned short)((u + 0x7fffu + ((u >> 16) & 1u)) >> 16);
}
DEVI unsigned char f2fp8(float f) {  // RNE float -> OCP e4m3fn
  uint32_t u = __builtin_bit_cast(uint32_t, f);
  uint32_t s = (u >> 24) & 0x80u;
  uint32_t a = u & 0x7fffffffu;
  if (a >= 0x43e00000u) return (unsigned char)(s | 0x7eu);  // sat to 448
  if (a < 0x3c800000u) {  // |f| < 2^-6 -> subnormal, step 2^-9
    float af = __builtin_bit_cast(float, a);
    uint32_t n = (uint32_t)__builtin_rintf(af * 512.0f);
    return (unsigned char)(s | n);
  }
  uint32_t r = a + 0xfffffu + ((a >> 20) & 1u);
  return (unsigned char)(s | ((r >> 20) - 960u));
}
DEVI float sigmoidf_(float x) { return 1.0f / (1.0f + expf(-x)); }

DEVI void gld16(const void* g, void* l) {
  __builtin_amdgcn_global_load_lds(
      (const __attribute__((address_space(1))) unsigned int*)g,
      (__attribute__((address_space(3))) unsigned int*)l, 16, 0, 0);
}

#define MFMA16B(a, b, c) __builtin_amdgcn_mfma_f32_16x16x32_bf16(a, b, c, 0, 0, 0)
#define MFMAMX(a, b, c)                                              \
  __builtin_amdgcn_mfma_scale_f32_16x16x128_f8f6f4(                  \
      a, b, c, 0, 0, 0, 0x7f7f7f7fu, 0, 0x7f7f7f7fu)

// ---------------------------------------------------------------------------
__global__ __launch_bounds__(256) void k_f32_to_bf16(
    const float* __restrict__ s, unsigned short* __restrict__ d, long n) {
  long i0 = ((long)blockIdx.x * 256 + threadIdx.x) * 8;
  long stride = (long)gridDim.x * 256 * 8;
  for (long i = i0; i < n; i += stride) {
    f32x4 a = *(const f32x4*)(s + i);
    f32x4 b = *(const f32x4*)(s + i + 4);
    ushort8 o;
    o[0] = f2bf(a[0]); o[1] = f2bf(a[1]); o[2] = f2bf(a[2]); o[3] = f2bf(a[3]);
    o[4] = f2bf(b[0]); o[5] = f2bf(b[1]); o[6] = f2bf(b[2]); o[7] = f2bf(b[3]);
    *(ushort8*)(d + i) = o;
  }
}

__global__ __launch_bounds__(256) void k_f32_to_fp8(
    const float* __restrict__ s, unsigned char* __restrict__ d, long n,
    float scale) {
  long i0 = ((long)blockIdx.x * 256 + threadIdx.x) * 8;
  long stride = (long)gridDim.x * 256 * 8;
  for (long i = i0; i < n; i += stride) {
    f32x4 a = *(const f32x4*)(s + i);
    f32x4 b = *(const f32x4*)(s + i + 4);
    uchar8 o;
    o[0] = f2fp8(a[0] * scale); o[1] = f2fp8(a[1] * scale);
    o[2] = f2fp8(a[2] * scale); o[3] = f2fp8(a[3] * scale);
    o[4] = f2fp8(b[0] * scale); o[5] = f2fp8(b[1] * scale);
    o[6] = f2fp8(b[2] * scale); o[7] = f2fp8(b[3] * scale);
    *(uchar8*)(d + i) = o;
  }
}

// ---------------------------------------------------------------------------
// MX-fp8 GEMM, 256x128 tile, BK=128, 8 waves (wave-tile 64x64), single-
// buffered 48KB LDS, 2 blocks/CU. C[M,N] = A[M,K]*B[N,K]^T, e4m3, K%128==0.
// LDS: A rows 0..255 @0 (32KB), B rows 0..127 @32768 (16KB). Row = 128 B
// (8 chunks of 16B); chunk c stored at c^(row&7) via inverse-swizzled global
// source (linear gld16 dest); frag reads XOR the same.
// Frag (16x16x128): lane l: row=l&15, k=(l>>4)*32+0..31 (2 b128 chunks).
// Waves: wr=wid>>1 (64-row band), wc=wid&1 (64-col band). acc[4][4]=64 AGPR.
// EPI 0: outF[z*zsf + row*N + col] = acc*dsc   (z = branch)
// EPI 1: outB[z] = e4m3(tanh(acc*dsc + bias[row]))
// ---------------------------------------------------------------------------
struct I4Pair { int4v lo, hi; };

template <int EPI>
__global__ __launch_bounds__(512, 4) void k_gemmMX(
    const unsigned char* __restrict__ A0, const unsigned char* __restrict__ A1,
    const unsigned char* __restrict__ B0, const unsigned char* __restrict__ B1,
    float* __restrict__ outF, unsigned char* __restrict__ oB0,
    unsigned char* __restrict__ oB1, const float* __restrict__ bias0,
    const float* __restrict__ bias1, int M, int N, int K, long zsf,
    float dsc) {
  // XCD-aware bijective swizzle of the xy-plane (plane size % 8 == 0)
  const int gx = gridDim.x;
  const int nwg = gx * gridDim.y;
  const int flat = blockIdx.y * gx + blockIdx.x;
  const int swz = (flat & 7) * (nwg >> 3) + (flat >> 3);
  const int bxi = swz % gx, byi = swz / gx;

  const int bz = blockIdx.z;
  const unsigned char* A = bz ? A1 : A0;
  const unsigned char* B = bz ? B1 : B0;
  unsigned char* outB = bz ? oB1 : oB0;
  const float* bias = bz ? bias1 : bias0;

  __shared__ unsigned char lds[49152];  // A 32KB @0, B 16KB @32768
  const int tid = threadIdx.x, lane = tid & 63;
  const int wid = tid >> 6, wr = wid >> 1, wc = wid & 1;
  const int bm = bxi * 256, bn = byi * 128;
  const int rl = lane & 15, q = lane >> 4;

  // fragment read offsets: two b128 chunks per 32B fragment
  const int x7 = rl & 7;
  const int c0 = ((2 * q) ^ x7) << 4;
  const int c1 = ((2 * q + 1) ^ x7) << 4;

  const unsigned char* gA = A + (size_t)bm * K;
  const unsigned char* gB = B + (size_t)bn * K;

  // 6 chunk-loads/thread: A chunks cid 0..2047, B chunks 2048..3071.
  // Addressing rematerialized from tid (anti-spill, R13/R14 lesson).
  auto stage = [&](int kc) {
#pragma unroll
    for (int i = 0; i < 4; i++) {
      const int cid = tid + 512 * i;
      const int r = cid >> 3;
      const int go = r * K + (((cid & 7) ^ (r & 7)) << 4) + kc;
      gld16(gA + go, &lds[cid << 4]);
    }
#pragma unroll
    for (int i = 4; i < 6; i++) {
      const int cid = tid + 512 * i;
      const int r = (cid - 2048) >> 3;
      const int go = r * K + (((cid & 7) ^ (r & 7)) << 4) + kc;
      gld16(gB + go, &lds[cid << 4]);
    }
  };

  f32x4 acc[4][4] = {};

  auto frag = [&](const unsigned char* p) {
    I4Pair t;
    t.lo = *(const int4v*)(p + c0);
    t.hi = *(const int4v*)(p + c1);
    return __builtin_bit_cast(int8v, t);
  };

  for (int k0 = 0; k0 < K; k0 += 128) {
    stage(k0);
    asm volatile("s_waitcnt vmcnt(0)\ns_barrier" ::: "memory");

    int8v bf[4];
#pragma unroll
    for (int nf = 0; nf < 4; nf++)
      bf[nf] = frag(lds + 32768 + (wc * 64 + nf * 16 + rl) * 128);

    __builtin_amdgcn_s_setprio(1);
#pragma unroll
    for (int mi = 0; mi < 4; mi++) {
      int8v a = frag(lds + (wr * 64 + mi * 16 + rl) * 128);
#pragma unroll
      for (int nf = 0; nf < 4; nf++)
        acc[mi][nf] = MFMAMX(a, bf[nf], acc[mi][nf]);
    }
    __builtin_amdgcn_s_setprio(0);

    if (k0 + 128 < K) {
      // all waves done reading before next stage overwrites the buffer
      asm volatile("s_barrier" ::: "memory");
    }
  }

#pragma unroll
  for (int m = 0; m < 4; m++) {
#pragma unroll
    for (int nf = 0; nf < 4; nf++) {
      const int col = bn + wc * 64 + nf * 16 + rl;
#pragma unroll
      for (int r = 0; r < 4; r++) {
        const int row = bm + wr * 64 + m * 16 + q * 4 + r;
        const float v = acc[m][nf][r] * dsc;
        if (EPI == 0)
          outF[(long)bz * zsf + (size_t)row * N + col] = v;
        else
          outB[(size_t)row * N + col] = f2fp8(tanhf(v + bias[row]));
      }
    }
  }
}

// ---------------------------------------------------------------------------
// h = e4m3(tanh(relu(x @ mw^T + mb))), fused over branches (z = branch).
// ---------------------------------------------------------------------------
__global__ __launch_bounds__(256) void k_gemmH(
    const unsigned short* __restrict__ A0, const unsigned short* __restrict__ A1,
    const unsigned short* __restrict__ B0, const unsigned short* __restrict__ B1,
    unsigned char* __restrict__ o0, unsigned char* __restrict__ o1,
    const float* __restrict__ bias0, const float* __restrict__ bias1, int M,
    int N, int K) {
  const int bz = blockIdx.z;
  const unsigned short* A = bz ? A1 : A0;
  const unsigned short* B = bz ? B1 : B0;
  unsigned char* out8 = bz ? o1 : o0;
  const float* bias = bz ? bias1 : bias0;

  __shared__ unsigned short As[128 * 32];
  __shared__ unsigned short Bs[128 * 32];
  const int tid = threadIdx.x, lane = tid & 63, wid = tid >> 6;
  const int wr = wid >> 1, wc = wid & 1;
  const int bm = blockIdx.x * 128, bn = blockIdx.y * 128;
  const int c0 = tid, c1 = tid + 256;
  const int s0 = ((c0 & 3) ^ ((c0 >> 3) & 3)) << 3;
  const int s1 = ((c1 & 3) ^ ((c1 >> 3) & 3)) << 3;
  const int rl = lane & 15, q = lane >> 4;
  const int qe = (q ^ ((rl >> 1) & 3)) << 3;

  f32x4 acc[4][4] = {};

  for (int k0 = 0; k0 < K; k0 += 32) {
    gld16(A + (size_t)(bm + (c0 >> 2)) * K + k0 + s0, As + c0 * 8);
    gld16(A + (size_t)(bm + (c1 >> 2)) * K + k0 + s1, As + c1 * 8);
    gld16(B + (size_t)(bn + (c0 >> 2)) * K + k0 + s0, Bs + c0 * 8);
    gld16(B + (size_t)(bn + (c1 >> 2)) * K + k0 + s1, Bs + c1 * 8);
    __syncthreads();

    short8 af[4], bfr[4];
#pragma unroll
    for (int mi = 0; mi < 4; mi++)
      af[mi] = *(const short8*)(As + (wr * 64 + mi * 16 + rl) * 32 + qe);
#pragma unroll
    for (int ni = 0; ni < 4; ni++)
      bfr[ni] = *(const short8*)(Bs + (wc * 64 + ni * 16 + rl) * 32 + qe);
#pragma unroll
    for (int mi = 0; mi < 4; mi++)
#pragma unroll
      for (int ni = 0; ni < 4; ni++)
        acc[mi][ni] = MFMA16B(af[mi], bfr[ni], acc[mi][ni]);
    __syncthreads();
  }

#pragma unroll
  for (int mi = 0; mi < 4; mi++) {
#pragma unroll
    for (int ni = 0; ni < 4; ni++) {
      const int col = bn + wc * 64 + ni * 16 + rl;
#pragma unroll
      for (int r = 0; r < 4; r++) {
        const int row = bm + wr * 64 + mi * 16 + q * 4 + r;
        out8[(size_t)row * N + col] =
            f2fp8(tanhf(fmaxf(acc[mi][ni][r] + bias[col], 0.0f)));
      }
    }
  }
}

// ---------------------------------------------------------------------------
// Skinny GEMM, N=64, split-K. grid: (M/64, KS, nbr)
// ---------------------------------------------------------------------------
template <int AMODE, int BMODE>
__global__ __launch_bounds__(256) void k_sgemm64s(
    const void* __restrict__ A0, const void* __restrict__ A1,
    const void* __restrict__ B0, const void* __restrict__ B1,
    float* __restrict__ P, int kchunk, int lda, int ldb, int M) {
  const int br = blockIdx.z, kz = blockIdx.y, KS = gridDim.y;
  const void* Av = br ? A1 : A0;
  const void* Bv = br ? B1 : B0;

  __shared__ unsigned short As[64 * 40];
  __shared__ unsigned short Bs[64 * 40];
  const int tid = threadIdx.x, lane = tid & 63, w = tid >> 6;
  const int tm = blockIdx.x * 64;

  f32x4 acc[4] = {};
  const int kbeg = kz * kchunk, kend = kbeg + kchunk;

  for (int k0 = kbeg; k0 < kend; k0 += 32) {
    if (AMODE == 0) {
      const float* Af = (const float*)Av;
      const int m = tid >> 2, k8 = (tid & 3) << 3;
      f32x4 x0 = *(const f32x4*)(Af + (size_t)(tm + m) * lda + k0 + k8);
      f32x4 x1 = *(const f32x4*)(Af + (size_t)(tm + m) * lda + k0 + k8 + 4);
      ushort8 o;
      o[0] = f2bf(x0[0]); o[1] = f2bf(x0[1]); o[2] = f2bf(x0[2]); o[3] = f2bf(x0[3]);
      o[4] = f2bf(x1[0]); o[5] = f2bf(x1[1]); o[6] = f2bf(x1[2]); o[7] = f2bf(x1[3]);
      *(ushort8*)(As + m * 40 + k8) = o;
    } else if (AMODE == 1) {
      const float* Af = (const float*)Av;
#pragma unroll
      for (int t = 0; t < 2; t++) {
        const int c = tid + t * 256;
        const int u = c >> 4, i4 = (c & 15) << 2;
        f32x4 x = *(const f32x4*)(Af + (size_t)(k0 + u) * lda + tm + i4);
        As[(i4 + 0) * 40 + u] = f2bf(x[0]);
        As[(i4 + 1) * 40 + u] = f2bf(x[1]);
        As[(i4 + 2) * 40 + u] = f2bf(x[2]);
        As[(i4 + 3) * 40 + u] = f2bf(x[3]);
      }
    } else {
      const unsigned short* Ab = (const unsigned short*)Av;
      const int m = tid >> 2, k8 = (tid & 3) << 3;
      *(ushort8*)(As + m * 40 + k8) =
          *(const ushort8*)(Ab + (size_t)(tm + m) * lda + k0 + k8);
    }
    if (BMODE == 0) {
      const float* Bf = (const float*)Bv;
      const int n = tid >> 2, k8 = (tid & 3) << 3;
      f32x4 x0 = *(const f32x4*)(Bf + (size_t)n * ldb + k0 + k8);
      f32x4 x1 = *(const f32x4*)(Bf + (size_t)n * ldb + k0 + k8 + 4);
      ushort8 o;
      o[0] = f2bf(x0[0]); o[1] = f2bf(x0[1]); o[2] = f2bf(x0[2]); o[3] = f2bf(x0[3]);
      o[4] = f2bf(x1[0]); o[5] = f2bf(x1[1]); o[6] = f2bf(x1[2]); o[7] = f2bf(x1[3]);
      *(ushort8*)(Bs + n * 40 + k8) = o;
    } else {
      const unsigned short* Bb = (const unsigned short*)Bv;
      const int n = tid >> 2, k8 = (tid & 3) << 3;
      *(ushort8*)(Bs + n * 40 + k8) =
          *(const ushort8*)(Bb + (size_t)n * ldb + k0 + k8);
    }
    __syncthreads();

    const int kr = (lane >> 4) << 3;
    short8 a = *(const short8*)(As + (w * 16 + (lane & 15)) * 40 + kr);
#pragma unroll
    for (int ni = 0; ni < 4; ni++) {
      short8 bb = *(const short8*)(Bs + (ni * 16 + (lane & 15)) * 40 + kr);
      acc[ni] = MFMA16B(a, bb, acc[ni]);
    }
    __syncthreads();
  }

  float* out = P + ((size_t)(br * KS + kz) * M) * 64;
#pragma unroll
  for (int ni = 0; ni < 4; ni++) {
    const int col = ni * 16 + (lane & 15);
#pragma unroll
    for (int r = 0; r < 4; r++) {
      const int row = tm + w * 16 + ((lane >> 4) << 2) + r;
      out[(size_t)row * 64 + col] = acc[ni][r];
    }
  }
}

// ---------------------------------------------------------------------------
template <int WF, int WB, int WT>
__global__ __launch_bounds__(256) void k_reduce(
    const float* __restrict__ P, size_t pbr_stride, float* F0, float* F1,
    unsigned short* Bo0, unsigned short* Bo1, unsigned short* T0,
    unsigned short* T1, int M, int KS, int ldT) {
  const int br = blockIdx.y;
  const float* Pp = P + (size_t)br * pbr_stride;
  const size_t i = (size_t)blockIdx.x * 256 + threadIdx.x;
  const size_t n = (size_t)M * 64;
  float s = 0.f;
  for (int k = 0; k < KS; k++) s += Pp[(size_t)k * n + i];
  if (WF) (br ? F1 : F0)[i] = s;
  if (WB) (br ? Bo1 : Bo0)[i] = f2bf(s);
  if (WT) {
    const int row = (int)(i >> 6), col = (int)(i & 63);
    (br ? T1 : T0)[(size_t)col * ldT + row] = f2bf(s);
  }
}

// ---------------------------------------------------------------------------
// Row softmax, single f32 slab per branch (z = branch): [2048,4096] -> bf16
// ---------------------------------------------------------------------------
__global__ __launch_bounds__(256) void k_softmax(
    const float* __restrict__ S, unsigned short* __restrict__ P0,
    unsigned short* __restrict__ P1, long slab) {
  const int row = blockIdx.x, br = blockIdx.y, tid = threadIdx.x;
  const float* s = S + (size_t)br * slab + (size_t)row * 4096;
  float v[16];
  float m = -1e30f;
#pragma unroll
  for (int j = 0; j < 16; j++) {
    v[j] = s[tid + j * 256];
    m = fmaxf(m, v[j]);
  }
  __shared__ float red[4], red2[4];
  for (int o = 32; o; o >>= 1) m = fmaxf(m, __shfl_down(m, o));
  if ((tid & 63) == 0) red[tid >> 6] = m;
  __syncthreads();
  m = fmaxf(fmaxf(red[0], red[1]), fmaxf(red[2], red[3]));
  float sum = 0.0f;
#pragma unroll
  for (int j = 0; j < 16; j++) {
    v[j] = expf(v[j] - m);
    sum += v[j];
  }
  for (int o = 32; o; o >>= 1) sum += __shfl_down(sum, o);
  if ((tid & 63) == 0) red2[tid >> 6] = sum;
  __syncthreads();
  const float inv = 1.0f / (red2[0] + red2[1] + red2[2] + red2[3]);
  unsigned short* p = (br ? P1 : P0) + (size_t)row * 4096;
#pragma unroll
  for (int j = 0; j < 16; j++) p[tid + j * 256] = f2bf(v[j] * inv);
}

// ---------------------------------------------------------------------------
__global__ __launch_bounds__(256) void k_user(
    const float* __restrict__ ue_mp, const float* __restrict__ ueat_mp,
    const float* __restrict__ ue_pmp, const float* __restrict__ ueat_pmp,
    const float* __restrict__ mlp_w, const float* __restrict__ mlp_b,
    const float* __restrict__ tr_w, const float* __restrict__ tr_b,
    float* __restrict__ out) {
  const int tid = threadIdx.x, d = tid & 63, w = tid >> 6;
  const int m = blockIdx.x * 4 + w;
  __shared__ float fus[4][64];
  float a1 = mlp_b[d], a2 = a1;
  const float* r1 = ue_mp + (size_t)m * 64;
  const float* r2 = ueat_mp + (size_t)m * 64;
  const float* r3 = ue_pmp + (size_t)m * 64;
  const float* r4 = ueat_pmp + (size_t)m * 64;
  const float* w1 = mlp_w + (size_t)d * 128;
#pragma unroll 8
  for (int k = 0; k < 64; k++) {
    const float wv = w1[k];
    a1 += r1[k] * wv;
    a2 += r3[k] * wv;
  }
#pragma unroll 8
  for (int k = 0; k < 64; k++) {
    const float wv = w1[64 + k];
    a1 += r2[k] * wv;
    a2 += r4[k] * wv;
  }
  const float u1 = sigmoidf_(a1), u2 = sigmoidf_(a2);
  const float rate = sigmoidf_(u1 + u2);
  fus[w][d] = rate * u1 + (1.0f - rate) * u2;
  __syncthreads();
  float o = tr_b[d];
  const float* tw = tr_w + (size_t)d * 64;
#pragma unroll 8
  for (int k = 0; k < 64; k++) o += fus[w][k] * tw[k];
  out[(size_t)m * 64 + d] = tanhf(o);
}

__global__ __launch_bounds__(256) void k_item(
    const float* __restrict__ ie_mp, const float* __restrict__ ie_pmp,
    const float* __restrict__ mlp_w, const float* __restrict__ mlp_b,
    float* __restrict__ out) {
  const int tid = threadIdx.x, d = tid & 63, w = tid >> 6;
  const int i = blockIdx.x * 4 + w;
  float a = mlp_b[d];
  const float* r1 = ie_mp + (size_t)i * 64;
  const float* r2 = ie_pmp + (size_t)i * 64;
  const float* wp = mlp_w + (size_t)d * 128;
#pragma unroll 8
  for (int k = 0; k < 64; k++) {
    a += r1[k] * wp[k];
    a += r2[k] * wp[64 + k];
  }
  out[(size_t)i * 64 + d] = sigmoidf_(a);
}

// ---------------------------------------------------------------------------
extern "C" void kernel_launch(void* const* d_in, const int* in_sizes, int n_in,
                              void* d_out, int out_size, void* d_ws,
                              size_t ws_size, hipStream_t stream) {
  const int U = 2048, I = 4096, D = 64, UI = 6144;
  const float WSC = 16.0f, DSC = 1.0f / 16.0f;

  const float* ui[2] = {(const float*)d_in[0], (const float*)d_in[1]};
  const float* Wu[2] = {(const float*)d_in[2], (const float*)d_in[3]};
  const float* Wi[2] = {(const float*)d_in[4], (const float*)d_in[5]};
  const float* mw[2] = {(const float*)d_in[6], (const float*)d_in[11]};
  const float* mb[2] = {(const float*)d_in[7], (const float*)d_in[12]};
  const float* aw[2] = {(const float*)d_in[8], (const float*)d_in[13]};
  const float* ab[2] = {(const float*)d_in[9], (const float*)d_in[14]};
  const float* Wat[2] = {(const float*)d_in[10], (const float*)d_in[15]};
  const float* mlp_w = (const float*)d_in[16];
  const float* mlp_b = (const float*)d_in[17];
  const float* tr_w = (const float*)d_in[18];
  const float* tr_b = (const float*)d_in[19];

  char* ws = (char*)d_ws;
  size_t off = 0;
  auto alloc = [&](size_t bytes) {
    void* p = ws + off;
    off += (bytes + 255) & ~(size_t)255;
    return p;
  };
  unsigned char* aw_f8[2] = {(unsigned char*)alloc((size_t)I * I),
                             (unsigned char*)alloc((size_t)I * I)};
  unsigned short* mw_bf[2] = {(unsigned short*)alloc((size_t)I * D * 2),
                              (unsigned short*)alloc((size_t)I * D * 2)};
  unsigned char* h_f8[2] = {(unsigned char*)alloc((size_t)UI * I),
                            (unsigned char*)alloc((size_t)UI * I)};
  unsigned char* aT_f8[2] = {(unsigned char*)alloc((size_t)I * UI),
                             (unsigned char*)alloc((size_t)I * UI)};
  float* scores = (float*)alloc((size_t)U * I * 4 * 2);  // 2 branch slabs
  unsigned short* at_bf[2] = {(unsigned short*)alloc((size_t)U * I * 2),
                              (unsigned short*)alloc((size_t)U * I * 2)};
  unsigned short* x_bf[2];
  float* ue_f[2];
  float* ie_f[2];
  unsigned short* ieT[2];
  float* ueat_f[2];
  for (int b = 0; b < 2; b++) {
    x_bf[b] = (unsigned short*)alloc((size_t)UI * D * 2);
    ue_f[b] = (float*)alloc((size_t)U * D * 4);
    ie_f[b] = (float*)alloc((size_t)I * D * 4);
    ieT[b] = (unsigned short*)alloc((size_t)D * I * 2);
    ueat_f[b] = (float*)alloc((size_t)U * D * 4);
  }
  // Lifetime aliases:
  //  pue (8.4MB)  -> h_f8[0] region (dead until h written)
  //  pie (16.8MB) -> aT_f8[0] region (dead until aT written)
  //  pueat (8.4MB)-> scores region (written after softmaxes read it)
  //  Wat_f8[b] (12.6MB) -> at_bf[b] region (written by softmax AFTER scores
  //  consumed Wat_f8 — stream-ordered, safe)
  float* pue = (float*)h_f8[0];
  float* pie = (float*)aT_f8[0];
  float* pueat = scores;
  unsigned char* Wat_f8[2] = {(unsigned char*)at_bf[0],
                              (unsigned char*)at_bf[1]};
  const long zsf = (long)U * I;

  const dim3 blk(256);

  // ue: [U,64] over K=I, both branches, KS=8
  k_sgemm64s<0, 0><<<dim3(U / 64, 8, 2), blk, 0, stream>>>(
      ui[0], ui[1], Wu[0], Wu[1], pue, I / 8, I, I, U);
  k_reduce<1, 1, 0><<<dim3(U * 64 / 256, 2), blk, 0, stream>>>(
      pue, (size_t)8 * U * 64, ue_f[0], ue_f[1], x_bf[0], x_bf[1], nullptr,
      nullptr, U, 8, 0);
  // ie: [I,64] over K=U (A = ui^T), both branches, KS=8
  k_sgemm64s<1, 0><<<dim3(I / 64, 8, 2), blk, 0, stream>>>(
      ui[0], ui[1], Wi[0], Wi[1], pie, U / 8, I, U, I);
  k_reduce<1, 1, 1><<<dim3(I * 64 / 256, 2), blk, 0, stream>>>(
      pie, (size_t)8 * I * 64, ie_f[0], ie_f[1], x_bf[0] + (size_t)U * D,
      x_bf[1] + (size_t)U * D, ieT[0], ieT[1], I, 8, I);

  // converts (all weights, both branches)
  for (int b = 0; b < 2; b++) {
    k_f32_to_fp8<<<2048, blk, 0, stream>>>(aw[b], aw_f8[b], (long)I * I, WSC);
    k_f32_to_fp8<<<2048, blk, 0, stream>>>(Wat[b], Wat_f8[b], (long)U * UI, WSC);
    k_f32_to_bf16<<<128, blk, 0, stream>>>(mw[b], mw_bf[b], (long)I * D);
  }

  // h both branches: [6144,4096], K=64 (z = branch)
  k_gemmH<<<dim3(UI / 128, I / 128, 2), blk, 0, stream>>>(
      x_bf[0], x_bf[1], mw_bf[0], mw_bf[1], h_f8[0], h_f8[1], mb[0], mb[1],
      UI, I, D);

  // aT both branches: [4096,6144], K=4096; (16,48,2)=1536 blocks
  k_gemmMX<1><<<dim3(I / 256, UI / 128, 2), dim3(512), 0, stream>>>(
      aw_f8[0], aw_f8[1], h_f8[0], h_f8[1], nullptr, aT_f8[0], aT_f8[1],
      ab[0], ab[1], I, UI, I, 0, DSC);

  // scores both branches: [2048,4096], K=6144; (8,32,2)=512 blocks
  k_gemmMX<0><<<dim3(U / 256, I / 128, 2), dim3(512), 0, stream>>>(
      Wat_f8[0], Wat_f8[1], aT_f8[0], aT_f8[1], scores, nullptr, nullptr,
      nullptr, nullptr, U, I, UI, zsf, DSC);

  // softmax both branches (clobbers Wat_f8 alias — Wat dead after scores)
  k_softmax<<<dim3(U, 2), blk, 0, stream>>>(scores, at_bf[0], at_bf[1], zsf);

  // ue_at both branches: [U,64] over K=I, KS=8
  k_sgemm64s<2, 2><<<dim3(U / 64, 8, 2), blk, 0, stream>>>(
      at_bf[0], at_bf[1], ieT[0], ieT[1], pueat, I / 8, I, I, U);
  k_reduce<1, 0, 0><<<dim3(U * 64 / 256, 2), blk, 0, stream>>>(
      pueat, (size_t)8 * U * 64, ueat_f[0], ueat_f[1], nullptr, nullptr,
      nullptr, nullptr, U, 8, 0);

  float* out_user = (float*)d_out;
  float* out_item = (float*)d_out + (size_t)U * D;
  k_user<<<U / 4, blk, 0, stream>>>(ue_f[0], ueat_f[0], ue_f[1], ueat_f[1],
                                    mlp_w, mlp_b, tr_w, tr_b, out_user);
  k_item<<<I / 4, blk, 0, stream>>>(ie_f[0], ie_f[1], mlp_w, mlp_b, out_item);
}

// Round 16
// 575.220 us; speedup vs baseline: 1.2792x; 1.0016x over previous
//
#include <hip/hip_runtime.h>
#include <stdint.h>
#include <math.h>

// ---------------------------------------------------------------------------
// PAAE layer, MI355X (gfx950). Round 15: 256x128 MX-fp8 GEMM @ 2 blocks/CU.
// R14 audit: 256^2 shape is register-pinned to 1 block/CU -> no cross-block
// overlap -> 34% of pipe floor; R10/R11 (2 blocks/CU) hit ~74%. New geometry:
// tile 256x128, 8 waves (wave-tile 64x64, acc=64 AGPR), single-buffered 48KB
// LDS, __launch_bounds__(512,4) caps 128 regs/wave -> 16 waves/CU = 2 blocks.
// R10's proven protocol: stage -> vmcnt(0)+barrier -> compute -> barrier.
// Grids: aT (16,48,2)=1536 (3 exact super-rounds), scores (8,32,2)=512.
// ---------------------------------------------------------------------------

typedef short short8 __attribute__((ext_vector_type(8)));
typedef unsigned short ushort8 __attribute__((ext_vector_type(8)));
typedef unsigned char uchar8 __attribute__((ext_vector_type(8)));
typedef float f32x4 __attribute__((ext_vector_type(4)));
typedef int int4v __attribute__((ext_vector_type(4)));
typedef int int8v __attribute__((ext_vector_type(8)));

#define DEVI static __device__ __forceinline__

DEVI unsigned short f2bf(float f) {  // RNE float -> bf16 bits
  uint32_t u = __builtin_bit_cast(uint32_t, f);
  return (unsigned short)((u + 0x7fffu + ((u >> 16) & 1u)) >> 16);
}
DEVI unsigned char f2fp8(float f) {  // RNE float -> OCP e4m3fn
  uint32_t u = __builtin_bit_cast(uint32_t, f);
  uint32_t s = (u >> 24) & 0x80u;
  uint32_t a = u & 0x7fffffffu;
  if (a >= 0x43e00000u) return (unsigned char)(s | 0x7eu);  // sat to 448
  if (a < 0x3c800000u) {  // |f| < 2^-6 -> subnormal, step 2^-9
    float af = __builtin_bit_cast(float, a);
    uint32_t n = (uint32_t)__builtin_rintf(af * 512.0f);
    return (unsigned char)(s | n);
  }
  uint32_t r = a + 0xfffffu + ((a >> 20) & 1u);
  return (unsigned char)(s | ((r >> 20) - 960u));
}
DEVI float sigmoidf_(float x) { return 1.0f / (1.0f + expf(-x)); }

DEVI void gld16(const void* g, void* l) {
  __builtin_amdgcn_global_load_lds(
      (const __attribute__((address_space(1))) unsigned int*)g,
      (__attribute__((address_space(3))) unsigned int*)l, 16, 0, 0);
}

#define MFMA16B(a, b, c) __builtin_amdgcn_mfma_f32_16x16x32_bf16(a, b, c, 0, 0, 0)
#define MFMAMX(a, b, c)                                              \
  __builtin_amdgcn_mfma_scale_f32_16x16x128_f8f6f4(                  \
      a, b, c, 0, 0, 0, 0x7f7f7f7fu, 0, 0x7f7f7f7fu)

// ---------------------------------------------------------------------------
__global__ __launch_bounds__(256) void k_f32_to_bf16(
    const float* __restrict__ s, unsigned short* __restrict__ d, long n) {
  long i0 = ((long)blockIdx.x * 256 + threadIdx.x) * 8;
  long stride = (long)gridDim.x * 256 * 8;
  for (long i = i0; i < n; i += stride) {
    f32x4 a = *(const f32x4*)(s + i);
    f32x4 b = *(const f32x4*)(s + i + 4);
    ushort8 o;
    o[0] = f2bf(a[0]); o[1] = f2bf(a[1]); o[2] = f2bf(a[2]); o[3] = f2bf(a[3]);
    o[4] = f2bf(b[0]); o[5] = f2bf(b[1]); o[6] = f2bf(b[2]); o[7] = f2bf(b[3]);
    *(ushort8*)(d + i) = o;
  }
}

__global__ __launch_bounds__(256) void k_f32_to_fp8(
    const float* __restrict__ s, unsigned char* __restrict__ d, long n,
    float scale) {
  long i0 = ((long)blockIdx.x * 256 + threadIdx.x) * 8;
  long stride = (long)gridDim.x * 256 * 8;
  for (long i = i0; i < n; i += stride) {
    f32x4 a = *(const f32x4*)(s + i);
    f32x4 b = *(const f32x4*)(s + i + 4);
    uchar8 o;
    o[0] = f2fp8(a[0] * scale); o[1] = f2fp8(a[1] * scale);
    o[2] = f2fp8(a[2] * scale); o[3] = f2fp8(a[3] * scale);
    o[4] = f2fp8(b[0] * scale); o[5] = f2fp8(b[1] * scale);
    o[6] = f2fp8(b[2] * scale); o[7] = f2fp8(b[3] * scale);
    *(uchar8*)(d + i) = o;
  }
}

// ---------------------------------------------------------------------------
// MX-fp8 GEMM, 256x128 tile, BK=128, 8 waves (wave-tile 64x64), single-
// buffered 48KB LDS, 2 blocks/CU. C[M,N] = A[M,K]*B[N,K]^T, e4m3, K%128==0.
// LDS: A rows 0..255 @0 (32KB), B rows 0..127 @32768 (16KB). Row = 128 B
// (8 chunks of 16B); chunk c stored at c^(row&7) via inverse-swizzled global
// source (linear gld16 dest); frag reads XOR the same.
// Frag (16x16x128): lane l: row=l&15, k=(l>>4)*32+0..31 (2 b128 chunks).
// Waves: wr=wid>>1 (64-row band), wc=wid&1 (64-col band). acc[4][4]=64 AGPR.
// EPI 0: outF[z*zsf + row*N + col] = acc*dsc   (z = branch)
// EPI 1: outB[z] = e4m3(tanh(acc*dsc + bias[row]))
// ---------------------------------------------------------------------------
struct I4Pair { int4v lo, hi; };

template <int EPI>
__global__ __launch_bounds__(512, 4) void k_gemmMX(
    const unsigned char* __restrict__ A0, const unsigned char* __restrict__ A1,
    const unsigned char* __restrict__ B0, const unsigned char* __restrict__ B1,
    float* __restrict__ outF, unsigned char* __restrict__ oB0,
    unsigned char* __restrict__ oB1, const float* __restrict__ bias0,
    const float* __restrict__ bias1, int M, int N, int K, long zsf,
    float dsc) {
  // XCD-aware bijective swizzle of the xy-plane (plane size % 8 == 0)
  const int gx = gridDim.x;
  const int nwg = gx * gridDim.y;
  const int flat = blockIdx.y * gx + blockIdx.x;
  const int swz = (flat & 7) * (nwg >> 3) + (flat >> 3);
  const int bxi = swz % gx, byi = swz / gx;

  const int bz = blockIdx.z;
  const unsigned char* A = bz ? A1 : A0;
  const unsigned char* B = bz ? B1 : B0;
  unsigned char* outB = bz ? oB1 : oB0;
  const float* bias = bz ? bias1 : bias0;

  __shared__ unsigned char lds[49152];  // A 32KB @0, B 16KB @32768
  const int tid = threadIdx.x, lane = tid & 63;
  const int wid = tid >> 6, wr = wid >> 1, wc = wid & 1;
  const int bm = bxi * 256, bn = byi * 128;
  const int rl = lane & 15, q = lane >> 4;

  // fragment read offsets: two b128 chunks per 32B fragment
  const int x7 = rl & 7;
  const int c0 = ((2 * q) ^ x7) << 4;
  const int c1 = ((2 * q + 1) ^ x7) << 4;

  const unsigned char* gA = A + (size_t)bm * K;
  const unsigned char* gB = B + (size_t)bn * K;

  // 6 chunk-loads/thread: A chunks cid 0..2047, B chunks 2048..3071.
  // Addressing rematerialized from tid (anti-spill, R13/R14 lesson).
  auto stage = [&](int kc) {
#pragma unroll
    for (int i = 0; i < 4; i++) {
      const int cid = tid + 512 * i;
      const int r = cid >> 3;
      const int go = r * K + (((cid & 7) ^ (r & 7)) << 4) + kc;
      gld16(gA + go, &lds[cid << 4]);
    }
#pragma unroll
    for (int i = 4; i < 6; i++) {
      const int cid = tid + 512 * i;
      const int r = (cid - 2048) >> 3;
      const int go = r * K + (((cid & 7) ^ (r & 7)) << 4) + kc;
      gld16(gB + go, &lds[cid << 4]);
    }
  };

  f32x4 acc[4][4] = {};

  auto frag = [&](const unsigned char* p) {
    I4Pair t;
    t.lo = *(const int4v*)(p + c0);
    t.hi = *(const int4v*)(p + c1);
    return __builtin_bit_cast(int8v, t);
  };

  for (int k0 = 0; k0 < K; k0 += 128) {
    stage(k0);
    asm volatile("s_waitcnt vmcnt(0)\ns_barrier" ::: "memory");

    int8v bf[4];
#pragma unroll
    for (int nf = 0; nf < 4; nf++)
      bf[nf] = frag(lds + 32768 + (wc * 64 + nf * 16 + rl) * 128);

    __builtin_amdgcn_s_setprio(1);
#pragma unroll
    for (int mi = 0; mi < 4; mi++) {
      int8v a = frag(lds + (wr * 64 + mi * 16 + rl) * 128);
#pragma unroll
      for (int nf = 0; nf < 4; nf++)
        acc[mi][nf] = MFMAMX(a, bf[nf], acc[mi][nf]);
    }
    __builtin_amdgcn_s_setprio(0);

    if (k0 + 128 < K) {
      // all waves done reading before next stage overwrites the buffer
      asm volatile("s_barrier" ::: "memory");
    }
  }

#pragma unroll
  for (int m = 0; m < 4; m++) {
#pragma unroll
    for (int nf = 0; nf < 4; nf++) {
      const int col = bn + wc * 64 + nf * 16 + rl;
#pragma unroll
      for (int r = 0; r < 4; r++) {
        const int row = bm + wr * 64 + m * 16 + q * 4 + r;
        const float v = acc[m][nf][r] * dsc;
        if (EPI == 0)
          outF[(long)bz * zsf + (size_t)row * N + col] = v;
        else
          outB[(size_t)row * N + col] = f2fp8(tanhf(v + bias[row]));
      }
    }
  }
}

// ---------------------------------------------------------------------------
// h = e4m3(tanh(relu(x @ mw^T + mb))), fused over branches (z = branch).
// ---------------------------------------------------------------------------
__global__ __launch_bounds__(256) void k_gemmH(
    const unsigned short* __restrict__ A0, const unsigned short* __restrict__ A1,
    const unsigned short* __restrict__ B0, const unsigned short* __restrict__ B1,
    unsigned char* __restrict__ o0, unsigned char* __restrict__ o1,
    const float* __restrict__ bias0, const float* __restrict__ bias1, int M,
    int N, int K) {
  const int bz = blockIdx.z;
  const unsigned short* A = bz ? A1 : A0;
  const unsigned short* B = bz ? B1 : B0;
  unsigned char* out8 = bz ? o1 : o0;
  const float* bias = bz ? bias1 : bias0;

  __shared__ unsigned short As[128 * 32];
  __shared__ unsigned short Bs[128 * 32];
  const int tid = threadIdx.x, lane = tid & 63, wid = tid >> 6;
  const int wr = wid >> 1, wc = wid & 1;
  const int bm = blockIdx.x * 128, bn = blockIdx.y * 128;
  const int c0 = tid, c1 = tid + 256;
  const int s0 = ((c0 & 3) ^ ((c0 >> 3) & 3)) << 3;
  const int s1 = ((c1 & 3) ^ ((c1 >> 3) & 3)) << 3;
  const int rl = lane & 15, q = lane >> 4;
  const int qe = (q ^ ((rl >> 1) & 3)) << 3;

  f32x4 acc[4][4] = {};

  for (int k0 = 0; k0 < K; k0 += 32) {
    gld16(A + (size_t)(bm + (c0 >> 2)) * K + k0 + s0, As + c0 * 8);
    gld16(A + (size_t)(bm + (c1 >> 2)) * K + k0 + s1, As + c1 * 8);
    gld16(B + (size_t)(bn + (c0 >> 2)) * K + k0 + s0, Bs + c0 * 8);
    gld16(B + (size_t)(bn + (c1 >> 2)) * K + k0 + s1, Bs + c1 * 8);
    __syncthreads();

    short8 af[4], bfr[4];
#pragma unroll
    for (int mi = 0; mi < 4; mi++)
      af[mi] = *(const short8*)(As + (wr * 64 + mi * 16 + rl) * 32 + qe);
#pragma unroll
    for (int ni = 0; ni < 4; ni++)
      bfr[ni] = *(const short8*)(Bs + (wc * 64 + ni * 16 + rl) * 32 + qe);
#pragma unroll
    for (int mi = 0; mi < 4; mi++)
#pragma unroll
      for (int ni = 0; ni < 4; ni++)
        acc[mi][ni] = MFMA16B(af[mi], bfr[ni], acc[mi][ni]);
    __syncthreads();
  }

#pragma unroll
  for (int mi = 0; mi < 4; mi++) {
#pragma unroll
    for (int ni = 0; ni < 4; ni++) {
      const int col = bn + wc * 64 + ni * 16 + rl;
#pragma unroll
      for (int r = 0; r < 4; r++) {
        const int row = bm + wr * 64 + mi * 16 + q * 4 + r;
        out8[(size_t)row * N + col] =
            f2fp8(tanhf(fmaxf(acc[mi][ni][r] + bias[col], 0.0f)));
      }
    }
  }
}

// ---------------------------------------------------------------------------
// Skinny GEMM, N=64, split-K. grid: (M/64, KS, nbr)
// ---------------------------------------------------------------------------
template <int AMODE, int BMODE>
__global__ __launch_bounds__(256) void k_sgemm64s(
    const void* __restrict__ A0, const void* __restrict__ A1,
    const void* __restrict__ B0, const void* __restrict__ B1,
    float* __restrict__ P, int kchunk, int lda, int ldb, int M) {
  const int br = blockIdx.z, kz = blockIdx.y, KS = gridDim.y;
  const void* Av = br ? A1 : A0;
  const void* Bv = br ? B1 : B0;

  __shared__ unsigned short As[64 * 40];
  __shared__ unsigned short Bs[64 * 40];
  const int tid = threadIdx.x, lane = tid & 63, w = tid >> 6;
  const int tm = blockIdx.x * 64;

  f32x4 acc[4] = {};
  const int kbeg = kz * kchunk, kend = kbeg + kchunk;

  for (int k0 = kbeg; k0 < kend; k0 += 32) {
    if (AMODE == 0) {
      const float* Af = (const float*)Av;
      const int m = tid >> 2, k8 = (tid & 3) << 3;
      f32x4 x0 = *(const f32x4*)(Af + (size_t)(tm + m) * lda + k0 + k8);
      f32x4 x1 = *(const f32x4*)(Af + (size_t)(tm + m) * lda + k0 + k8 + 4);
      ushort8 o;
      o[0] = f2bf(x0[0]); o[1] = f2bf(x0[1]); o[2] = f2bf(x0[2]); o[3] = f2bf(x0[3]);
      o[4] = f2bf(x1[0]); o[5] = f2bf(x1[1]); o[6] = f2bf(x1[2]); o[7] = f2bf(x1[3]);
      *(ushort8*)(As + m * 40 + k8) = o;
    } else if (AMODE == 1) {
      const float* Af = (const float*)Av;
#pragma unroll
      for (int t = 0; t < 2; t++) {
        const int c = tid + t * 256;
        const int u = c >> 4, i4 = (c & 15) << 2;
        f32x4 x = *(const f32x4*)(Af + (size_t)(k0 + u) * lda + tm + i4);
        As[(i4 + 0) * 40 + u] = f2bf(x[0]);
        As[(i4 + 1) * 40 + u] = f2bf(x[1]);
        As[(i4 + 2) * 40 + u] = f2bf(x[2]);
        As[(i4 + 3) * 40 + u] = f2bf(x[3]);
      }
    } else {
      const unsigned short* Ab = (const unsigned short*)Av;
      const int m = tid >> 2, k8 = (tid & 3) << 3;
      *(ushort8*)(As + m * 40 + k8) =
          *(const ushort8*)(Ab + (size_t)(tm + m) * lda + k0 + k8);
    }
    if (BMODE == 0) {
      const float* Bf = (const float*)Bv;
      const int n = tid >> 2, k8 = (tid & 3) << 3;
      f32x4 x0 = *(const f32x4*)(Bf + (size_t)n * ldb + k0 + k8);
      f32x4 x1 = *(const f32x4*)(Bf + (size_t)n * ldb + k0 + k8 + 4);
      ushort8 o;
      o[0] = f2bf(x0[0]); o[1] = f2bf(x0[1]); o[2] = f2bf(x0[2]); o[3] = f2bf(x0[3]);
      o[4] = f2bf(x1[0]); o[5] = f2bf(x1[1]); o[6] = f2bf(x1[2]); o[7] = f2bf(x1[3]);
      *(ushort8*)(Bs + n * 40 + k8) = o;
    } else {
      const unsigned short* Bb = (const unsigned short*)Bv;
      const int n = tid >> 2, k8 = (tid & 3) << 3;
      *(ushort8*)(Bs + n * 40 + k8) =
          *(const ushort8*)(Bb + (size_t)n * ldb + k0 + k8);
    }
    __syncthreads();

    const int kr = (lane >> 4) << 3;
    short8 a = *(const short8*)(As + (w * 16 + (lane & 15)) * 40 + kr);
#pragma unroll
    for (int ni = 0; ni < 4; ni++) {
      short8 bb = *(const short8*)(Bs + (ni * 16 + (lane & 15)) * 40 + kr);
      acc[ni] = MFMA16B(a, bb, acc[ni]);
    }
    __syncthreads();
  }

  float* out = P + ((size_t)(br * KS + kz) * M) * 64;
#pragma unroll
  for (int ni = 0; ni < 4; ni++) {
    const int col = ni * 16 + (lane & 15);
#pragma unroll
    for (int r = 0; r < 4; r++) {
      const int row = tm + w * 16 + ((lane >> 4) << 2) + r;
      out[(size_t)row * 64 + col] = acc[ni][r];
    }
  }
}

// ---------------------------------------------------------------------------
template <int WF, int WB, int WT>
__global__ __launch_bounds__(256) void k_reduce(
    const float* __restrict__ P, size_t pbr_stride, float* F0, float* F1,
    unsigned short* Bo0, unsigned short* Bo1, unsigned short* T0,
    unsigned short* T1, int M, int KS, int ldT) {
  const int br = blockIdx.y;
  const float* Pp = P + (size_t)br * pbr_stride;
  const size_t i = (size_t)blockIdx.x * 256 + threadIdx.x;
  const size_t n = (size_t)M * 64;
  float s = 0.f;
  for (int k = 0; k < KS; k++) s += Pp[(size_t)k * n + i];
  if (WF) (br ? F1 : F0)[i] = s;
  if (WB) (br ? Bo1 : Bo0)[i] = f2bf(s);
  if (WT) {
    const int row = (int)(i >> 6), col = (int)(i & 63);
    (br ? T1 : T0)[(size_t)col * ldT + row] = f2bf(s);
  }
}

// ---------------------------------------------------------------------------
// Row softmax, single f32 slab per branch (z = branch): [2048,4096] -> bf16
// ---------------------------------------------------------------------------
__global__ __launch_bounds__(256) void k_softmax(
    const float* __restrict__ S, unsigned short* __restrict__ P0,
    unsigned short* __restrict__ P1, long slab) {
  const int row = blockIdx.x, br = blockIdx.y, tid = threadIdx.x;
  const float* s = S + (size_t)br * slab + (size_t)row * 4096;
  float v[16];
  float m = -1e30f;
#pragma unroll
  for (int j = 0; j < 16; j++) {
    v[j] = s[tid + j * 256];
    m = fmaxf(m, v[j]);
  }
  __shared__ float red[4], red2[4];
  for (int o = 32; o; o >>= 1) m = fmaxf(m, __shfl_down(m, o));
  if ((tid & 63) == 0) red[tid >> 6] = m;
  __syncthreads();
  m = fmaxf(fmaxf(red[0], red[1]), fmaxf(red[2], red[3]));
  float sum = 0.0f;
#pragma unroll
  for (int j = 0; j < 16; j++) {
    v[j] = expf(v[j] - m);
    sum += v[j];
  }
  for (int o = 32; o; o >>= 1) sum += __shfl_down(sum, o);
  if ((tid & 63) == 0) red2[tid >> 6] = sum;
  __syncthreads();
  const float inv = 1.0f / (red2[0] + red2[1] + red2[2] + red2[3]);
  unsigned short* p = (br ? P1 : P0) + (size_t)row * 4096;
#pragma unroll
  for (int j = 0; j < 16; j++) p[tid + j * 256] = f2bf(v[j] * inv);
}

// ---------------------------------------------------------------------------
__global__ __launch_bounds__(256) void k_user(
    const float* __restrict__ ue_mp, const float* __restrict__ ueat_mp,
    const float* __restrict__ ue_pmp, const float* __restrict__ ueat_pmp,
    const float* __restrict__ mlp_w, const float* __restrict__ mlp_b,
    const float* __restrict__ tr_w, const float* __restrict__ tr_b,
    float* __restrict__ out) {
  const int tid = threadIdx.x, d = tid & 63, w = tid >> 6;
  const int m = blockIdx.x * 4 + w;
  __shared__ float fus[4][64];
  float a1 = mlp_b[d], a2 = a1;
  const float* r1 = ue_mp + (size_t)m * 64;
  const float* r2 = ueat_mp + (size_t)m * 64;
  const float* r3 = ue_pmp + (size_t)m * 64;
  const float* r4 = ueat_pmp + (size_t)m * 64;
  const float* w1 = mlp_w + (size_t)d * 128;
#pragma unroll 8
  for (int k = 0; k < 64; k++) {
    const float wv = w1[k];
    a1 += r1[k] * wv;
    a2 += r3[k] * wv;
  }
#pragma unroll 8
  for (int k = 0; k < 64; k++) {
    const float wv = w1[64 + k];
    a1 += r2[k] * wv;
    a2 += r4[k] * wv;
  }
  const float u1 = sigmoidf_(a1), u2 = sigmoidf_(a2);
  const float rate = sigmoidf_(u1 + u2);
  fus[w][d] = rate * u1 + (1.0f - rate) * u2;
  __syncthreads();
  float o = tr_b[d];
  const float* tw = tr_w + (size_t)d * 64;
#pragma unroll 8
  for (int k = 0; k < 64; k++) o += fus[w][k] * tw[k];
  out[(size_t)m * 64 + d] = tanhf(o);
}

__global__ __launch_bounds__(256) void k_item(
    const float* __restrict__ ie_mp, const float* __restrict__ ie_pmp,
    const float* __restrict__ mlp_w, const float* __restrict__ mlp_b,
    float* __restrict__ out) {
  const int tid = threadIdx.x, d = tid & 63, w = tid >> 6;
  const int i = blockIdx.x * 4 + w;
  float a = mlp_b[d];
  const float* r1 = ie_mp + (size_t)i * 64;
  const float* r2 = ie_pmp + (size_t)i * 64;
  const float* wp = mlp_w + (size_t)d * 128;
#pragma unroll 8
  for (int k = 0; k < 64; k++) {
    a += r1[k] * wp[k];
    a += r2[k] * wp[64 + k];
  }
  out[(size_t)i * 64 + d] = sigmoidf_(a);
}

// ---------------------------------------------------------------------------
extern "C" void kernel_launch(void* const* d_in, const int* in_sizes, int n_in,
                              void* d_out, int out_size, void* d_ws,
                              size_t ws_size, hipStream_t stream) {
  const int U = 2048, I = 4096, D = 64, UI = 6144;
  const float WSC = 16.0f, DSC = 1.0f / 16.0f;

  const float* ui[2] = {(const float*)d_in[0], (const float*)d_in[1]};
  const float* Wu[2] = {(const float*)d_in[2], (const float*)d_in[3]};
  const float* Wi[2] = {(const float*)d_in[4], (const float*)d_in[5]};
  const float* mw[2] = {(const float*)d_in[6], (const float*)d_in[11]};
  const float* mb[2] = {(const float*)d_in[7], (const float*)d_in[12]};
  const float* aw[2] = {(const float*)d_in[8], (const float*)d_in[13]};
  const float* ab[2] = {(const float*)d_in[9], (const float*)d_in[14]};
  const float* Wat[2] = {(const float*)d_in[10], (const float*)d_in[15]};
  const float* mlp_w = (const float*)d_in[16];
  const float* mlp_b = (const float*)d_in[17];
  const float* tr_w = (const float*)d_in[18];
  const float* tr_b = (const float*)d_in[19];

  char* ws = (char*)d_ws;
  size_t off = 0;
  auto alloc = [&](size_t bytes) {
    void* p = ws + off;
    off += (bytes + 255) & ~(size_t)255;
    return p;
  };
  unsigned char* aw_f8[2] = {(unsigned char*)alloc((size_t)I * I),
                             (unsigned char*)alloc((size_t)I * I)};
  unsigned short* mw_bf[2] = {(unsigned short*)alloc((size_t)I * D * 2),
                              (unsigned short*)alloc((size_t)I * D * 2)};
  unsigned char* h_f8[2] = {(unsigned char*)alloc((size_t)UI * I),
                            (unsigned char*)alloc((size_t)UI * I)};
  unsigned char* aT_f8[2] = {(unsigned char*)alloc((size_t)I * UI),
                             (unsigned char*)alloc((size_t)I * UI)};
  float* scores = (float*)alloc((size_t)U * I * 4 * 2);  // 2 branch slabs
  unsigned short* at_bf[2] = {(unsigned short*)alloc((size_t)U * I * 2),
                              (unsigned short*)alloc((size_t)U * I * 2)};
  unsigned short* x_bf[2];
  float* ue_f[2];
  float* ie_f[2];
  unsigned short* ieT[2];
  float* ueat_f[2];
  for (int b = 0; b < 2; b++) {
    x_bf[b] = (unsigned short*)alloc((size_t)UI * D * 2);
    ue_f[b] = (float*)alloc((size_t)U * D * 4);
    ie_f[b] = (float*)alloc((size_t)I * D * 4);
    ieT[b] = (unsigned short*)alloc((size_t)D * I * 2);
    ueat_f[b] = (float*)alloc((size_t)U * D * 4);
  }
  // Lifetime aliases:
  //  pue (8.4MB)  -> h_f8[0] region (dead until h written)
  //  pie (16.8MB) -> aT_f8[0] region (dead until aT written)
  //  pueat (8.4MB)-> scores region (written after softmaxes read it)
  //  Wat_f8[b] (12.6MB) -> at_bf[b] region (written by softmax AFTER scores
  //  consumed Wat_f8 — stream-ordered, safe)
  float* pue = (float*)h_f8[0];
  float* pie = (float*)aT_f8[0];
  float* pueat = scores;
  unsigned char* Wat_f8[2] = {(unsigned char*)at_bf[0],
                              (unsigned char*)at_bf[1]};
  const long zsf = (long)U * I;

  const dim3 blk(256);

  // ue: [U,64] over K=I, both branches, KS=8
  k_sgemm64s<0, 0><<<dim3(U / 64, 8, 2), blk, 0, stream>>>(
      ui[0], ui[1], Wu[0], Wu[1], pue, I / 8, I, I, U);
  k_reduce<1, 1, 0><<<dim3(U * 64 / 256, 2), blk, 0, stream>>>(
      pue, (size_t)8 * U * 64, ue_f[0], ue_f[1], x_bf[0], x_bf[1], nullptr,
      nullptr, U, 8, 0);
  // ie: [I,64] over K=U (A = ui^T), both branches, KS=8
  k_sgemm64s<1, 0><<<dim3(I / 64, 8, 2), blk, 0, stream>>>(
      ui[0], ui[1], Wi[0], Wi[1], pie, U / 8, I, U, I);
  k_reduce<1, 1, 1><<<dim3(I * 64 / 256, 2), blk, 0, stream>>>(
      pie, (size_t)8 * I * 64, ie_f[0], ie_f[1], x_bf[0] + (size_t)U * D,
      x_bf[1] + (size_t)U * D, ieT[0], ieT[1], I, 8, I);

  // converts (all weights, both branches)
  for (int b = 0; b < 2; b++) {
    k_f32_to_fp8<<<2048, blk, 0, stream>>>(aw[b], aw_f8[b], (long)I * I, WSC);
    k_f32_to_fp8<<<2048, blk, 0, stream>>>(Wat[b], Wat_f8[b], (long)U * UI, WSC);
    k_f32_to_bf16<<<128, blk, 0, stream>>>(mw[b], mw_bf[b], (long)I * D);
  }

  // h both branches: [6144,4096], K=64 (z = branch)
  k_gemmH<<<dim3(UI / 128, I / 128, 2), blk, 0, stream>>>(
      x_bf[0], x_bf[1], mw_bf[0], mw_bf[1], h_f8[0], h_f8[1], mb[0], mb[1],
      UI, I, D);

  // aT both branches: [4096,6144], K=4096; (16,48,2)=1536 blocks
  k_gemmMX<1><<<dim3(I / 256, UI / 128, 2), dim3(512), 0, stream>>>(
      aw_f8[0], aw_f8[1], h_f8[0], h_f8[1], nullptr, aT_f8[0], aT_f8[1],
      ab[0], ab[1], I, UI, I, 0, DSC);

  // scores both branches: [2048,4096], K=6144; (8,32,2)=512 blocks
  k_gemmMX<0><<<dim3(U / 256, I / 128, 2), dim3(512), 0, stream>>>(
      Wat_f8[0], Wat_f8[1], aT_f8[0], aT_f8[1], scores, nullptr, nullptr,
      nullptr, nullptr, U, I, UI, zsf, DSC);

  // softmax both branches (clobbers Wat_f8 alias — Wat dead after scores)
  k_softmax<<<dim3(U, 2), blk, 0, stream>>>(scores, at_bf[0], at_bf[1], zsf);

  // ue_at both branches: [U,64] over K=I, KS=8
  k_sgemm64s<2, 2><<<dim3(U / 64, 8, 2), blk, 0, stream>>>(
      at_bf[0], at_bf[1], ieT[0], ieT[1], pueat, I / 8, I, I, U);
  k_reduce<1, 0, 0><<<dim3(U * 64 / 256, 2), blk, 0, stream>>>(
      pueat, (size_t)8 * U * 64, ueat_f[0], ueat_f[1], nullptr, nullptr,
      nullptr, nullptr, U, 8, 0);

  float* out_user = (float*)d_out;
  float* out_item = (float*)d_out + (size_t)U * D;
  k_user<<<U / 4, blk, 0, stream>>>(ue_f[0], ueat_f[0], ue_f[1], ueat_f[1],
                                    mlp_w, mlp_b, tr_w, tr_b, out_user);
  k_item<<<I / 4, blk, 0, stream>>>(ie_f[0], ie_f[1], mlp_w, mlp_b, out_item);
}